// Round 1
// 33765.680 us; speedup vs baseline: 1.0850x; 1.0850x over previous
//
#include <hip/hip_runtime.h>

#define HID 1024
#define FEAT 128
#define BAT 128
#define NSAMP 96
#define NPRED 8
#define GD 4096                    // 4*HID
#define MB (NSAMP * BAT)           // 12288
#define SLOTE ((size_t)BAT * HID)  // 131072 elements per 128-row state slot
#define PREDT 16384                // elements per pred tile (4 panels)

typedef unsigned short u16;
typedef unsigned int u32;
typedef unsigned long long u64;
typedef short bf16x8 __attribute__((ext_vector_type(8)));
typedef float f32x4 __attribute__((ext_vector_type(4)));

__device__ inline u16 f2bf(float f) {
    unsigned u = __float_as_uint(f);
    u += 0x7FFFu + ((u >> 16) & 1u);
    return (u16)(u >> 16);
}
__device__ inline float bf2f(u16 h) { return __uint_as_float(((unsigned)h) << 16); }
__device__ inline float fsig(float x) { return 1.0f / (1.0f + __expf(-x)); }
__device__ inline float ftanh(float x) { return 1.0f - 2.0f / (__expf(2.0f * x) + 1.0f); }

// Panel-major layout everywhere: a [R rows][K] matrix is stored as
// [K/32 panels][R=128 rows][32 k] bf16; each panel = 8 KB contiguous.
// States: slot-panel (panel = unit-chunk). Weights: per-output-stripe panels.

__device__ inline void gl2lds16(const u16* g, u16* l) {
    __builtin_amdgcn_global_load_lds(
        (const __attribute__((address_space(1))) u32*)g,
        (__attribute__((address_space(3))) u32*)l, 16, 0, 0);
}

// Coherent 16B load as 2x8B agent-scope relaxed atomic loads: bypasses L1/L2
// (reads the coherence point) so NO L2-invalidating acquire fence is needed.
// Used ONLY for cross-block chain-state reads; weights stay plain/cached.
__device__ inline uint4 cload16(const u16* p) {
    u64 lo = __hip_atomic_load((const u64*)p, __ATOMIC_RELAXED, __HIP_MEMORY_SCOPE_AGENT);
    u64 hi = __hip_atomic_load(((const u64*)p) + 1, __ATOMIC_RELAXED, __HIP_MEMORY_SCOPE_AGENT);
    uint4 r;
    r.x = (u32)lo; r.y = (u32)(lo >> 32);
    r.z = (u32)hi; r.w = (u32)(hi >> 32);
    return r;
}

__device__ inline u64 pack4bf(u16 a, u16 b, u16 c, u16 d) {
    return (u64)a | ((u64)b << 16) | ((u64)c << 32) | ((u64)d << 48);
}

// ---- per-block flags: word (l,step,b) at ((l*97+step)*32+b)*32 ints ----
#define FLAGN (2 * 97 * 32 * 32)
__device__ inline void waitset(const int* base) {
    const int tid = threadIdx.x;
    if (tid < 64) {
        long t = 0;
        for (;;) {
            int v = (tid < 32)
                ? __hip_atomic_load(base + tid * 32, __ATOMIC_RELAXED, __HIP_MEMORY_SCOPE_AGENT)
                : 1;
            if (__all(v != 0)) break;
            __builtin_amdgcn_s_sleep(2);
            if (++t > 3000000L) break;   // bounded: fail loud (wrong answer), not hang
        }
    }
    // workgroup fence only: state reads use agent-scope atomic loads (L2-bypass),
    // so the per-step agent acquire (= full per-XCD L2 invalidate that was
    // flushing the cached weight stripes every step) is no longer needed.
    __builtin_amdgcn_fence(__ATOMIC_ACQUIRE, "workgroup");
    __syncthreads();
}

#define LDSS 40  // phase-A padded LDS row stride (shorts)

union SMemA {
    struct { u16 a[2][128 * LDSS]; u16 b[2][128 * LDSS]; } st;
    float g[32][132];
};

// =====================================================================
// Phase A: persistent 2-layer filter chain. 64 blocks: b<32 -> L0 panel
// b; b>=32 -> L1. c in registers. Per-block flags.
// Coherence scheme: chainH written with write-through agent atomic
// stores; consumers read it with agent atomic loads; weights/bias/input
// stay plain loads and remain L1/L2-resident across all 96 steps.
// =====================================================================
__global__ __launch_bounds__(256, 1) void lstm_chain(
    const float* __restrict__ inMusic,
    const u16* __restrict__ Wih0p, const u16* __restrict__ Whh0p,
    const u16* __restrict__ Wih1p, const u16* __restrict__ Whh1p,
    const float* __restrict__ bp0, const float* __restrict__ bp1,
    const float* __restrict__ c0,
    u16* __restrict__ chainH, u16* __restrict__ chainCb,
    float* __restrict__ h_std, float* __restrict__ c_std,
    int* __restrict__ flags)
{
    __shared__ SMemA sm;
    const int blk = blockIdx.x;
    const int l = blk >> 5, tn = blk & 31;
    const int tid = threadIdx.x;
    const int wave = tid >> 6, lane = tid & 63;
    const int wm = wave >> 1, wn = wave & 1;
    const int quad = lane >> 4, lc = lane & 15;
    const int rl = tid >> 3, ub = (tid & 7) * 4;
    const int br = tid >> 2, bc = (tid & 3) * 8;

    // panel-major weight stripes
    const u16* BihS = (l ? Wih1p : Wih0p) + (size_t)tn * 128 * (l ? HID : FEAT);
    const u16* BhhS = (l ? Whh1p : Whh0p) + (size_t)tn * 128 * HID;
    const float* bias = l ? bp1 : bp0;
    auto fw = [&](int ll, int s) { return flags + ((size_t)(ll * 97 + s) * 32) * 32; };

    float creg[4][4];
#pragma unroll
    for (int i = 0; i < 4; ++i) {
        int lrow = (rl >> 4) * 64 + i * 16 + (rl & 15);
        float4 c4 = *(const float4*)(c0 + (size_t)l * SLOTE + (size_t)lrow * HID + tn * 32 + ub);
        creg[i][0] = c4.x; creg[i][1] = c4.y; creg[i][2] = c4.z; creg[i][3] = c4.w;
    }
    float bv[4];
#pragma unroll
    for (int j = 0; j < 4; ++j) bv[j] = bias[tn * 128 + wn * 64 + j * 16 + lc];

    for (int k = 0; k < NSAMP; ++k) {
        const int rk = (k <= 1) ? 0 : k;
        if (l == 0) { waitset(fw(0, rk)); }
        else       { waitset(fw(0, k + 1)); waitset(fw(1, rk)); }

        f32x4 acc[4][4];
#pragma unroll
        for (int j = 0; j < 4; ++j) {
            f32x4 bvv = {bv[j], bv[j], bv[j], bv[j]};
#pragma unroll
            for (int i = 0; i < 4; ++i) acc[i][j] = bvv;
        }

        auto mfma_panels = [&]() {
#pragma unroll
            for (int p = 0; p < 2; ++p) {
                bf16x8 aF[4], bF[4];
#pragma unroll
                for (int i = 0; i < 4; ++i)
                    aF[i] = *(const bf16x8*)&sm.st.a[p][(wm * 64 + i * 16 + lc) * LDSS + quad * 8];
#pragma unroll
                for (int j = 0; j < 4; ++j)
                    bF[j] = *(const bf16x8*)&sm.st.b[p][(wn * 64 + j * 16 + lc) * LDSS + quad * 8];
#pragma unroll
                for (int i = 0; i < 4; ++i)
#pragma unroll
                    for (int j = 0; j < 4; ++j)
                        acc[i][j] = __builtin_amdgcn_mfma_f32_16x16x32_bf16(aF[i], bF[j], acc[i][j], 0, 0, 0);
            }
        };

        // panel-major offset (same for state A and weight B)
        auto po = [&](int row, int k0, int h) -> size_t {
            return ((size_t)((k0 >> 5) + h) * 128 + row) * 32 + bc;
        };
        // A (chain state, cross-block fresh) -> coherent atomic loads;
        // B (weights, immutable) -> plain cached loads.
        auto kloop_sp = [&](const u16* Ab, const u16* Bb) {
            uint4 aR[2][2], bR[2][2];
#pragma unroll
            for (int it = 0; it < 2; ++it)
#pragma unroll
                for (int h = 0; h < 2; ++h) {
                    aR[it][h] = cload16(Ab + po(it * 64 + br, 0, h));
                    bR[it][h] = *(const uint4*)(Bb + po(it * 64 + br, 0, h));
                }
            for (int ii = 0; ii < 16; ++ii) {
                __syncthreads();
#pragma unroll
                for (int it = 0; it < 2; ++it)
#pragma unroll
                    for (int h = 0; h < 2; ++h) {
                        *(uint4*)&sm.st.a[h][(it * 64 + br) * LDSS + bc] = aR[it][h];
                        *(uint4*)&sm.st.b[h][(it * 64 + br) * LDSS + bc] = bR[it][h];
                    }
                if (ii + 1 < 16) {
                    int k0 = (ii + 1) * 64;
#pragma unroll
                    for (int it = 0; it < 2; ++it)
#pragma unroll
                        for (int h = 0; h < 2; ++h) {
                            aR[it][h] = cload16(Ab + po(it * 64 + br, k0, h));
                            bR[it][h] = *(const uint4*)(Bb + po(it * 64 + br, k0, h));
                        }
                }
                __syncthreads();
                mfma_panels();
            }
        };

        if (l == 0) {
            const float* Af = inMusic + (size_t)k * BAT * FEAT;
            const int ar = tid >> 4, ac = (tid & 15) * 4;
            const int apan = ac >> 5, alc = ac & 31;
            float4 aR[8]; uint4 bR[2][2];
#pragma unroll
            for (int it = 0; it < 8; ++it)
                aR[it] = *(const float4*)(Af + (size_t)(it * 16 + ar) * FEAT + ac);
#pragma unroll
            for (int it = 0; it < 2; ++it)
#pragma unroll
                for (int h = 0; h < 2; ++h)
                    bR[it][h] = *(const uint4*)(BihS + po(it * 64 + br, 0, h));
            for (int ii = 0; ii < 2; ++ii) {
                __syncthreads();
#pragma unroll
                for (int it = 0; it < 8; ++it) {
                    ushort4 pk = make_ushort4(f2bf(aR[it].x), f2bf(aR[it].y),
                                              f2bf(aR[it].z), f2bf(aR[it].w));
                    *(ushort4*)&sm.st.a[apan][(it * 16 + ar) * LDSS + alc] = pk;
                }
#pragma unroll
                for (int it = 0; it < 2; ++it)
#pragma unroll
                    for (int h = 0; h < 2; ++h)
                        *(uint4*)&sm.st.b[h][(it * 64 + br) * LDSS + bc] = bR[it][h];
                if (ii == 0) {
#pragma unroll
                    for (int it = 0; it < 8; ++it)
                        aR[it] = *(const float4*)(Af + (size_t)(it * 16 + ar) * FEAT + ac + 64);
#pragma unroll
                    for (int it = 0; it < 2; ++it)
#pragma unroll
                        for (int h = 0; h < 2; ++h)
                            bR[it][h] = *(const uint4*)(BihS + po(it * 64 + br, 64, h));
                }
                __syncthreads();
                mfma_panels();
            }
            kloop_sp(chainH + (size_t)rk * SLOTE, BhhS);
        } else {
            kloop_sp(chainH + (size_t)(k + 1) * SLOTE, BihS);
            kloop_sp(chainH + (size_t)(97 + rk) * SLOTE, BhhS);
        }

        __syncthreads();   // sG aliases staging panels
        size_t slotBase = (size_t)(l * 97 + k + 1) * SLOTE;
#pragma unroll 1
        for (int i = 0; i < 4; ++i) {
#pragma unroll
            for (int j = 0; j < 4; ++j)
#pragma unroll
                for (int r = 0; r < 4; ++r)
                    sm.g[wm * 16 + quad * 4 + r][wn * 64 + j * 16 + lc] = acc[i][j][r];
            __syncthreads();
            int lrow = (rl >> 4) * 64 + i * 16 + (rl & 15);
            size_t pOff = slotBase + ((size_t)tn * 128 + lrow) * 32 + ub;
            float c2v[4], h2v[4];
#pragma unroll
            for (int uu = 0; uu < 4; ++uu) {
                float4 gg = *(const float4*)&sm.g[rl][(ub + uu) * 4];
                float iv = fsig(gg.x), fv = fsig(gg.y), gv = ftanh(gg.z), ov = fsig(gg.w);
                float c2 = fv * creg[i][uu] + iv * gv;
                if (k != 0) creg[i][uu] = c2;    // filter update only for k>=1
                c2v[uu] = c2;
                h2v[uu] = ov * ftanh(c2);
            }
            // h chain: write-through agent store (visible at coherence point,
            // never dirty in L2 -> release wbl2 has nothing to flush)
            __hip_atomic_store((u64*)(chainH + pOff),
                               pack4bf(f2bf(h2v[0]), f2bf(h2v[1]), f2bf(h2v[2]), f2bf(h2v[3])),
                               __ATOMIC_RELAXED, __HIP_MEMORY_SCOPE_AGENT);
            // c chain: consumed only by the NEXT kernel (gemm_b) -> plain store
            *(ushort4*)(chainCb + pOff) =
                make_ushort4(f2bf(c2v[0]), f2bf(c2v[1]), f2bf(c2v[2]), f2bf(c2v[3]));
            if (k == 95) {
                size_t sOff = (size_t)l * SLOTE + (size_t)lrow * HID + tn * 32 + ub;
                *(float4*)(h_std + sOff) = make_float4(h2v[0], h2v[1], h2v[2], h2v[3]);
                *(float4*)(c_std + sOff) = make_float4(c2v[0], c2v[1], c2v[2], c2v[3]);
            }
            __syncthreads();
        }
        // release: all block stores drained (barrier above), then flag store
        if (tid == 0)
            __hip_atomic_store(fw(l, k + 1) + tn * 32, 1,
                               __ATOMIC_RELEASE, __HIP_MEMORY_SCOPE_AGENT);
    }
}

// =====================================================================
// Phase B: GEMM+LSTM, global_load_lds staging, all sources panel-major.
// pers=1: 768 blocks, tn=bx&31, 4 tm tiles. pers=0: grid (tn, tm).
// =====================================================================
struct GArgs {
    const u16* A1; const u16* A2;
    const u16 *B1, *B2;
    const float* bias;
    const u16* c_in; u16* cout_b;
    u16* h_out;
    u16* lin_out;
    int KP1, KP2;          // panels (K/32) per seg; 0 = absent
    int as1, as2;          // A tile stride (elements)
    int mode;
};

__global__ __launch_bounds__(256, 3) void gemm_b(GArgs g, int pers)
{
    __shared__ u16 sA[8192], sB[8192];
    __shared__ float sG[32][132];
    const int tid = threadIdx.x;
    const int wave = tid >> 6, lane = tid & 63;
    const int wm = wave >> 1, wn = wave & 1;
    const int quad = lane >> 4, lc = lane & 15;
    const int nt = pers ? 4 : 1;
    const int tn = pers ? (blockIdx.x & 31) : blockIdx.x;
    const int tm0 = pers ? ((blockIdx.x >> 5) * 4) : blockIdx.y;

    for (int t = 0; t < nt; ++t) {
        const int tm = tm0 + t;
        f32x4 acc[4][4];
#pragma unroll
        for (int j = 0; j < 4; ++j) {
            float bvx = g.bias[tn * 128 + wn * 64 + j * 16 + lc];
            f32x4 bvv = {bvx, bvx, bvx, bvx};
#pragma unroll
            for (int i = 0; i < 4; ++i) acc[i][j] = bvv;
        }

        for (int seg = 0; seg < 2; ++seg) {
            const int KP = seg ? g.KP2 : g.KP1;
            if (!KP) continue;
            const u16* Ap = seg ? (g.A2 + (size_t)tm * g.as2)
                                : (g.A1 + (size_t)tm * g.as1);
            const u16* Bp = (seg ? g.B2 : g.B1) + (size_t)tn * KP * 4096;
            const int NIT = KP >> 1;
            for (int ii = 0; ii < NIT; ++ii) {
                __syncthreads();                       // LDS free (prior reads done)
                const u16* ga = Ap + (size_t)ii * 8192;
                const u16* gb = Bp + (size_t)ii * 8192;
#pragma unroll
                for (int c4 = 0; c4 < 4; ++c4) {
                    int ch = wave * 4 + c4;            // 16 chunks x 512 elems
                    gl2lds16(ga + ch * 512 + lane * 8, &sA[ch * 512]);
                    gl2lds16(gb + ch * 512 + lane * 8, &sB[ch * 512]);
                }
                __syncthreads();                       // vmcnt(0) drain -> data ready
#pragma unroll
                for (int p = 0; p < 2; ++p) {
                    bf16x8 aF[4], bF[4];
#pragma unroll
                    for (int i = 0; i < 4; ++i)
                        aF[i] = *(const bf16x8*)&sA[p * 4096 + (wm * 64 + i * 16 + lc) * 32 + quad * 8];
#pragma unroll
                    for (int j = 0; j < 4; ++j)
                        bF[j] = *(const bf16x8*)&sB[p * 4096 + (wn * 64 + j * 16 + lc) * 32 + quad * 8];
#pragma unroll
                    for (int i = 0; i < 4; ++i)
#pragma unroll
                        for (int j = 0; j < 4; ++j)
                            acc[i][j] = __builtin_amdgcn_mfma_f32_16x16x32_bf16(aF[i], bF[j], acc[i][j], 0, 0, 0);
                }
            }
        }

        if (g.mode == 0) {
            const int rl = tid >> 3, ub = (tid & 7) * 4;
#pragma unroll 1
            for (int i = 0; i < 4; ++i) {
#pragma unroll
                for (int j = 0; j < 4; ++j)
#pragma unroll
                    for (int r = 0; r < 4; ++r)
                        sG[wm * 16 + quad * 4 + r][wn * 64 + j * 16 + lc] = acc[i][j][r];
                __syncthreads();
                int lrow = (rl >> 4) * 64 + i * 16 + (rl & 15);
                size_t pOff = (size_t)tm * SLOTE + ((size_t)tn * 128 + lrow) * 32 + ub;
                ushort4 co = *(const ushort4*)(g.c_in + pOff);
                float cold[4] = {bf2f(co.x), bf2f(co.y), bf2f(co.z), bf2f(co.w)};
                float c2v[4], h2v[4];
#pragma unroll
                for (int uu = 0; uu < 4; ++uu) {
                    float4 gg = *(const float4*)&sG[rl][(ub + uu) * 4];
                    float iv = fsig(gg.x), fv = fsig(gg.y), gv = ftanh(gg.z), ov = fsig(gg.w);
                    float c2 = fv * cold[uu] + iv * gv;
                    c2v[uu] = c2;
                    h2v[uu] = ov * ftanh(c2);
                }
                *(ushort4*)(g.cout_b + pOff) =
                    make_ushort4(f2bf(c2v[0]), f2bf(c2v[1]), f2bf(c2v[2]), f2bf(c2v[3]));
                *(ushort4*)(g.h_out + pOff) =
                    make_ushort4(f2bf(h2v[0]), f2bf(h2v[1]), f2bf(h2v[2]), f2bf(h2v[3]));
                __syncthreads();
            }
        } else {
            // lin: write pred tile in panel-major [tm][4][128][32]
#pragma unroll
            for (int i = 0; i < 4; ++i)
#pragma unroll
                for (int j = 0; j < 4; ++j)
#pragma unroll
                    for (int r = 0; r < 4; ++r) {
                        int grow = wm * 64 + i * 16 + quad * 4 + r;
                        int gcol = wn * 64 + j * 16 + lc;
                        size_t addr = (size_t)tm * PREDT + (size_t)(gcol >> 5) * 4096
                                    + (size_t)grow * 32 + (gcol & 31);
                        g.lin_out[addr] = f2bf(acc[i][j][r]);
                    }
        }
    }
}

// ---- setup / epilogue kernels ----
// panel-major weight convert; permute=1 applies gate interleave (i,f,g,o)
__global__ void convert_weight(const float* __restrict__ src, u16* __restrict__ dst,
                               int kshift, int permute, int total) {
    int idx = blockIdx.x * 256 + threadIdx.x;
    if (idx >= total) return;
    int kk = idx & 31;
    int r = (idx >> 5) & 127;
    int kp = (idx >> 12) & ((1 << (kshift - 5)) - 1);
    int stripe = idx >> (7 + kshift);
    int jp = stripe * 128 + r;
    int srow = permute ? ((jp & 3) * HID + (jp >> 2)) : jp;
    dst[idx] = f2bf(src[((size_t)srow << kshift) + kp * 32 + kk]);
}

__global__ void combine_bias(const float* __restrict__ bi, const float* __restrict__ bh,
                             float* __restrict__ dst) {
    int j = blockIdx.x * 256 + threadIdx.x;  // 4096
    int s = (j & 3) * HID + (j >> 2);
    dst[j] = bi[s] + bh[s];
}

__global__ void init_state(const float* __restrict__ h0, u16* __restrict__ chainH) {
    int idx = blockIdx.x * 256 + threadIdx.x;  // 2*BAT*HID
    int l = idx >> 17;
    int r = idx & (int)(SLOTE - 1);
    int b = r >> 10, hh = r & 1023;
    size_t po = ((size_t)(hh >> 5) * 128 + b) * 32 + (hh & 31);
    chainH[(size_t)l * 97 * SLOTE + po] = f2bf(h0[idx]);
}

__global__ void init_flags(int* __restrict__ f) {
    int gid = blockIdx.x * 256 + threadIdx.x;
    if (gid >= FLAGN) return;
    int step = (gid >> 10) % 97;             // flag word stride 32 ints; 32 blocks/step
    f[gid] = ((gid & 31) == 0 && step == 0) ? 1 : 0;
}

__global__ void copy_next(const u16* __restrict__ predsb, float* __restrict__ out) {
    int idx = blockIdx.x * 256 + threadIdx.x;  // BAT*FEAT
    int b = idx >> 7, f = idx & 127;
    out[idx] = bf2f(predsb[(size_t)95 * PREDT + (size_t)(f >> 5) * 4096 + b * 32 + (f & 31)]);
}

__global__ void gather_out(const float* __restrict__ inMusic, const u16* __restrict__ predsb,
                           float* __restrict__ outM) {
    int idx = blockIdx.x * 256 + threadIdx.x;  // 96*128*128*8
    int n = idx & 7;
    int f = (idx >> 3) & 127;
    int b = (idx >> 10) & 127;
    int r = idx >> 17;
    float v = 0.0f;
    if (r < NPRED && n >= r) {
        v = inMusic[((size_t)r * BAT + b) * FEAT + f];
    } else {
        int k = r - n - 1;
        if (n < k)
            v = bf2f(predsb[(size_t)n * NSAMP * PREDT + (size_t)k * PREDT
                            + (size_t)(f >> 5) * 4096 + b * 32 + (f & 31)]);
    }
    outM[idx] = v;
}

__global__ void zero_out(float* __restrict__ o, int nmax) {
    int idx = blockIdx.x * 256 + threadIdx.x;
    if (idx < nmax) o[idx] = 0.0f;
}

extern "C" void kernel_launch(void* const* d_in, const int* in_sizes, int n_in,
                              void* d_out, int out_size, void* d_ws, size_t ws_size,
                              hipStream_t stream) {
    (void)in_sizes; (void)n_in;
    const float* inMusic = (const float*)d_in[0];
    const float* h0   = (const float*)d_in[1];
    const float* c0   = (const float*)d_in[2];
    const float* Wih0 = (const float*)d_in[3];
    const float* Whh0 = (const float*)d_in[4];
    const float* bih0 = (const float*)d_in[5];
    const float* bhh0 = (const float*)d_in[6];
    const float* Wih1 = (const float*)d_in[7];
    const float* Whh1 = (const float*)d_in[8];
    const float* bih1 = (const float*)d_in[9];
    const float* bhh1 = (const float*)d_in[10];
    const float* Wlin = (const float*)d_in[11];
    const float* blin = (const float*)d_in[12];
    float* out = (float*)d_out;

    const size_t OUT_H = (size_t)NSAMP * BAT * FEAT * NPRED;
    const size_t OUT_C = OUT_H + 2 * SLOTE;
    const size_t OUT_NEXT = OUT_C + 2 * SLOTE;

    char* ws = (char*)d_ws;
    size_t off = 0;
    auto alloc = [&](size_t bytes) {
        void* p = ws + off;
        off = (off + bytes + 255) & ~(size_t)255;
        return p;
    };
    u16* Wih0p = (u16*)alloc((size_t)GD * FEAT * 2);
    u16* Whh0p = (u16*)alloc((size_t)GD * HID * 2);
    u16* Wih1p = (u16*)alloc((size_t)GD * HID * 2);
    u16* Whh1p = (u16*)alloc((size_t)GD * HID * 2);
    u16* Wlinb = (u16*)alloc((size_t)FEAT * HID * 2);
    float* bp0 = (float*)alloc(GD * 4);
    float* bp1 = (float*)alloc(GD * 4);
    u16* chainH  = (u16*)alloc((size_t)2 * 97 * SLOTE * 2);
    u16* chainCb = (u16*)alloc((size_t)2 * 97 * SLOTE * 2);
    u16* hp2 = (u16*)alloc((size_t)2 * (size_t)NSAMP * SLOTE * 2);
    u16* predsb = (u16*)alloc((size_t)NPRED * NSAMP * PREDT * 2);
    int* flags = (int*)alloc((size_t)FLAGN * 4);

    if (off > ws_size) {
        zero_out<<<(out_size + 255) / 256, 256, 0, stream>>>(out, out_size);
        return;
    }

    convert_weight<<<(GD * FEAT + 255) / 256, 256, 0, stream>>>(Wih0, Wih0p, 7, 1, GD * FEAT);
    convert_weight<<<(GD * HID + 255) / 256, 256, 0, stream>>>(Whh0, Whh0p, 10, 1, GD * HID);
    convert_weight<<<(GD * HID + 255) / 256, 256, 0, stream>>>(Wih1, Wih1p, 10, 1, GD * HID);
    convert_weight<<<(GD * HID + 255) / 256, 256, 0, stream>>>(Whh1, Whh1p, 10, 1, GD * HID);
    convert_weight<<<(FEAT * HID + 255) / 256, 256, 0, stream>>>(Wlin, Wlinb, 10, 0, FEAT * HID);
    combine_bias<<<GD / 256, 256, 0, stream>>>(bih0, bhh0, bp0);
    combine_bias<<<GD / 256, 256, 0, stream>>>(bih1, bhh1, bp1);
    init_state<<<(int)(2 * SLOTE) / 256, 256, 0, stream>>>(h0, chainH);
    init_flags<<<(FLAGN + 255) / 256, 256, 0, stream>>>(flags);

    lstm_chain<<<64, 256, 0, stream>>>(
        inMusic, Wih0p, Whh0p, Wih1p, Whh1p, bp0, bp1, c0,
        chainH, chainCb, out + OUT_H, out + OUT_C, flags);

    auto Hs = [&](int l, int s) { return chainH + ((size_t)l * 97 + s) * SLOTE; };
    auto Cs = [&](int l, int s) { return chainCb + ((size_t)l * 97 + s) * SLOTE; };

    u16* hbuf0[2] = {Hs(0, 1), Hs(1, 1)};
    u16* hbuf1[2] = {hp2, hp2 + (size_t)NSAMP * SLOTE};
    u16* cB[2] = {Cs(0, 1), Cs(1, 1)};

    auto mkLin = [&](const u16* src, u16* dst) {
        GArgs a = {};
        a.A1 = src; a.KP1 = 32; a.as1 = (int)SLOTE; a.KP2 = 0;
        a.B1 = Wlinb; a.bias = blin;
        a.lin_out = dst; a.mode = 1;
        return a;
    };
    auto mkB = [&](int l, const u16* A1, int kp1, int as1, const u16* A2, u16* nxt) {
        GArgs a = {};
        a.A1 = A1; a.KP1 = kp1; a.as1 = as1;
        a.A2 = A2; a.KP2 = 32; a.as2 = (int)SLOTE;
        a.B1 = (l == 0) ? Wih0p : Wih1p; a.B2 = (l == 0) ? Whh0p : Whh1p;
        a.bias = (l == 0) ? bp0 : bp1;
        a.c_in = cB[l]; a.cout_b = cB[l];
        a.h_out = nxt; a.mode = 0;
        return a;
    };

    gemm_b<<<dim3(1, 96), 256, 0, stream>>>(mkLin(hbuf0[1], predsb), 0);
    copy_next<<<(BAT * FEAT) / 256, 256, 0, stream>>>(predsb, out + OUT_NEXT);

    for (int n = 1; n < NPRED; ++n) {
        u16* cur0 = (n & 1) ? hbuf0[0] : hbuf1[0];
        u16* cur1 = (n & 1) ? hbuf0[1] : hbuf1[1];
        u16* nxt0 = (n & 1) ? hbuf1[0] : hbuf0[0];
        u16* nxt1 = (n & 1) ? hbuf1[1] : hbuf0[1];
        const u16* pin = predsb + (size_t)(n - 1) * NSAMP * PREDT;
        u16* pout = predsb + (size_t)n * NSAMP * PREDT;
        gemm_b<<<768, 256, 0, stream>>>(mkB(0, pin, 4, PREDT, cur0, nxt0), 1);
        gemm_b<<<768, 256, 0, stream>>>(mkB(1, nxt0, 32, (int)SLOTE, cur1, nxt1), 1);
        gemm_b<<<dim3(1, 96), 256, 0, stream>>>(mkLin(nxt1, pout), 0);
    }

    gather_out<<<(NSAMP * BAT * FEAT * NPRED) / 256, 256, 0, stream>>>(inMusic, predsb, out);
}

// Round 3
// 26653.433 us; speedup vs baseline: 1.3746x; 1.2668x over previous
//
#include <hip/hip_runtime.h>

#define HID 1024
#define FEAT 128
#define BAT 128
#define NSAMP 96
#define NPRED 8
#define GD 4096                    // 4*HID
#define MB (NSAMP * BAT)           // 12288
#define SLOTE ((size_t)BAT * HID)  // 131072 elements per 128-row state slot
#define PREDT 16384                // elements per pred tile (4 panels)

typedef unsigned short u16;
typedef unsigned int u32;
typedef unsigned long long u64;
typedef short bf16x8 __attribute__((ext_vector_type(8)));
typedef float f32x4 __attribute__((ext_vector_type(4)));

__device__ inline u16 f2bf(float f) {
    unsigned u = __float_as_uint(f);
    u += 0x7FFFu + ((u >> 16) & 1u);
    return (u16)(u >> 16);
}
__device__ inline float bf2f(u16 h) { return __uint_as_float(((unsigned)h) << 16); }
__device__ inline float fsig(float x) { return 1.0f / (1.0f + __expf(-x)); }
__device__ inline float ftanh(float x) { return 1.0f - 2.0f / (__expf(2.0f * x) + 1.0f); }

// Panel-major layout everywhere: a [R rows][K] matrix is stored as
// [K/32 panels][R=128 rows][32 k] bf16; each panel = 8 KB contiguous.

__device__ inline void gl2lds16(const u16* g, u16* l) {
    __builtin_amdgcn_global_load_lds(
        (const __attribute__((address_space(1))) u32*)g,
        (__attribute__((address_space(3))) u32*)l, 16, 0, 0);
}

// Coherent 16B load as 2x8B agent-scope relaxed atomic loads, FORCED to
// address_space(1) so they lower to global_atomic (vmcnt-only), never flat
// (flat counts in lgkmcnt and would make every MFMA fragment-read's counted
// lgkm wait drain in-flight state prefetches). Bypasses L1/L2 -> reads the
// coherence point; no acquire-invalidate needed anywhere in the loop.
__device__ inline uint4 cload16(const u16* p) {
    auto q = (const __attribute__((address_space(1))) u64*)p;
    u64 lo = __hip_atomic_load(q, __ATOMIC_RELAXED, __HIP_MEMORY_SCOPE_AGENT);
    u64 hi = __hip_atomic_load(q + 1, __ATOMIC_RELAXED, __HIP_MEMORY_SCOPE_AGENT);
    uint4 r;
    r.x = (u32)lo; r.y = (u32)(lo >> 32);
    r.z = (u32)hi; r.w = (u32)(hi >> 32);
    return r;
}

// Write-through agent-scope relaxed atomic 8B store (address_space(1)):
// acks from the coherence point, never dirty in L2 -> no wbl2 needed to
// publish it. ALL producer-side chain-state stores use this.
__device__ inline void cstore8(u16* p, u64 v) {
    __hip_atomic_store((__attribute__((address_space(1))) u64*)p, v,
                       __ATOMIC_RELAXED, __HIP_MEMORY_SCOPE_AGENT);
}

__device__ inline u64 pack4bf(u16 a, u16 b, u16 c, u16 d) {
    return (u64)a | ((u64)b << 16) | ((u64)c << 32) | ((u64)d << 48);
}

__device__ inline void lgkm0() { asm volatile("s_waitcnt lgkmcnt(0)" ::: "memory"); }

// ---- per-block flags: word (l,step,b) at ((l*97+step)*32+b)*32 ints ----
#define FLAGN (2 * 97 * 32 * 32)
__device__ inline void waitset(const int* base) {
    const int tid = threadIdx.x;
    if (tid < 64) {
        long t = 0;
        for (;;) {
            int v = (tid < 32)
                ? __hip_atomic_load(base + tid * 32, __ATOMIC_RELAXED, __HIP_MEMORY_SCOPE_AGENT)
                : 1;
            if (__all(v != 0)) break;
            __builtin_amdgcn_s_sleep(2);
            if (++t > 3000000L) break;   // bounded: fail loud (wrong answer), not hang
        }
    }
    // workgroup fence only: state reads use agent-scope atomic loads (L2-bypass).
    __builtin_amdgcn_fence(__ATOMIC_ACQUIRE, "workgroup");
    __syncthreads();
}

#define LDSS 40  // phase-A padded LDS row stride (shorts)

union SMemA {
    struct { u16 a[2][128 * LDSS]; u16 b[2][128 * LDSS]; } st;
    float g[32][132];
};

// =====================================================================
// Phase A: persistent 2-layer filter chain. 64 blocks: b<32 -> L0 panel
// b; b>=32 -> L1. c in registers. Per-block flags.
// Coherence: chainH+chainCb written with write-through agent atomics;
// consumers read chainH with agent atomic loads; weights/bias/input are
// plain cached loads (L1/L2-resident across all 96 steps). Flag store is
// RELAXED: the epilogue's final __syncthreads drains vmcnt(0) for every
// wave, so all write-through stores are at the coherence point before the
// flag is set -> no buffer_wbl2 L2 tag-walk on the serial critical path.
// K-loop: 2-deep register prefetch with raw s_barrier (no vmcnt(0) drain),
// so state loads stay in flight across 2 full MFMA phases.
// =====================================================================
__global__ __launch_bounds__(256, 1) void lstm_chain(
    const float* __restrict__ inMusic,
    const u16* __restrict__ Wih0p, const u16* __restrict__ Whh0p,
    const u16* __restrict__ Wih1p, const u16* __restrict__ Whh1p,
    const float* __restrict__ bp0, const float* __restrict__ bp1,
    const float* __restrict__ c0,
    u16* __restrict__ chainH, u16* __restrict__ chainCb,
    float* __restrict__ h_std, float* __restrict__ c_std,
    int* __restrict__ flags)
{
    __shared__ SMemA sm;
    const int blk = blockIdx.x;
    const int l = blk >> 5, tn = blk & 31;
    const int tid = threadIdx.x;
    const int wave = tid >> 6, lane = tid & 63;
    const int wm = wave >> 1, wn = wave & 1;
    const int quad = lane >> 4, lc = lane & 15;
    const int rl = tid >> 3, ub = (tid & 7) * 4;
    const int br = tid >> 2, bc = (tid & 3) * 8;

    // panel-major weight stripes
    const u16* BihS = (l ? Wih1p : Wih0p) + (size_t)tn * 128 * (l ? HID : FEAT);
    const u16* BhhS = (l ? Whh1p : Whh0p) + (size_t)tn * 128 * HID;
    const float* bias = l ? bp1 : bp0;
    auto fw = [&](int ll, int s) { return flags + ((size_t)(ll * 97 + s) * 32) * 32; };

    float creg[4][4];
#pragma unroll
    for (int i = 0; i < 4; ++i) {
        int lrow = (rl >> 4) * 64 + i * 16 + (rl & 15);
        float4 c4 = *(const float4*)(c0 + (size_t)l * SLOTE + (size_t)lrow * HID + tn * 32 + ub);
        creg[i][0] = c4.x; creg[i][1] = c4.y; creg[i][2] = c4.z; creg[i][3] = c4.w;
    }
    float bv[4];
#pragma unroll
    for (int j = 0; j < 4; ++j) bv[j] = bias[tn * 128 + wn * 64 + j * 16 + lc];

    for (int k = 0; k < NSAMP; ++k) {
        const int rk = (k <= 1) ? 0 : k;
        if (l == 0) { waitset(fw(0, rk)); }
        else       { waitset(fw(0, k + 1)); waitset(fw(1, rk)); }

        f32x4 acc[4][4];
#pragma unroll
        for (int j = 0; j < 4; ++j) {
            f32x4 bvv = {bv[j], bv[j], bv[j], bv[j]};
#pragma unroll
            for (int i = 0; i < 4; ++i) acc[i][j] = bvv;
        }

        auto mfma_panels = [&]() {
#pragma unroll
            for (int p = 0; p < 2; ++p) {
                bf16x8 aF[4], bF[4];
#pragma unroll
                for (int i = 0; i < 4; ++i)
                    aF[i] = *(const bf16x8*)&sm.st.a[p][(wm * 64 + i * 16 + lc) * LDSS + quad * 8];
#pragma unroll
                for (int j = 0; j < 4; ++j)
                    bF[j] = *(const bf16x8*)&sm.st.b[p][(wn * 64 + j * 16 + lc) * LDSS + quad * 8];
#pragma unroll
                for (int i = 0; i < 4; ++i)
#pragma unroll
                    for (int j = 0; j < 4; ++j)
                        acc[i][j] = __builtin_amdgcn_mfma_f32_16x16x32_bf16(aF[i], bF[j], acc[i][j], 0, 0, 0);
            }
        };

        // panel-major offset (same for state A and weight B)
        auto po = [&](int row, int k0, int h) -> size_t {
            return ((size_t)((k0 >> 5) + h) * 128 + row) * 32 + bc;
        };
        auto loadC = [&](uint4 (&aR)[2][2], uint4 (&bR)[2][2],
                         const u16* Ab, const u16* Bb, int k0) {
#pragma unroll
            for (int it = 0; it < 2; ++it)
#pragma unroll
                for (int h = 0; h < 2; ++h) {
                    aR[it][h] = cload16(Ab + po(it * 64 + br, k0, h));
                    bR[it][h] = *(const uint4*)(Bb + po(it * 64 + br, k0, h));
                }
        };
        auto writeC = [&](uint4 (&aR)[2][2], uint4 (&bR)[2][2]) {
#pragma unroll
            for (int it = 0; it < 2; ++it)
#pragma unroll
                for (int h = 0; h < 2; ++h) {
                    *(uint4*)&sm.st.a[h][(it * 64 + br) * LDSS + bc] = aR[it][h];
                    *(uint4*)&sm.st.b[h][(it * 64 + br) * LDSS + bc] = bR[it][h];
                }
        };
        // K=1024: 16 chunks of 64-K; 2-deep named-set prefetch pipeline.
        // Raw s_barrier (NOT __syncthreads): no vmcnt(0) drain, so prefetch
        // loads issued here stay outstanding across 2 MFMA phases and are
        // consumed via the compiler's counted vmcnt waits at writeC.
        // bar1 (before writeC): waves arrive only after their fragment
        //   ds_reads were consumed by MFMA -> LDS free to overwrite.
        // bar2 (after writeC): own ds_writes drained via lgkmcnt(0) first.
        auto kloop_sp = [&](const u16* Ab, const u16* Bb) {
            uint4 aE[2][2], bE[2][2], aO[2][2], bO[2][2];
            loadC(aE, bE, Ab, Bb, 0);
            loadC(aO, bO, Ab, Bb, 64);
            for (int ii = 0; ii < 16; ii += 2) {
                __builtin_amdgcn_s_barrier();
                writeC(aE, bE);
                lgkm0();
                __builtin_amdgcn_s_barrier();
                if (ii + 2 < 16) loadC(aE, bE, Ab, Bb, (ii + 2) * 64);
                mfma_panels();
                __builtin_amdgcn_s_barrier();
                writeC(aO, bO);
                lgkm0();
                __builtin_amdgcn_s_barrier();
                if (ii + 3 < 16) loadC(aO, bO, Ab, Bb, (ii + 3) * 64);
                mfma_panels();
            }
        };

        if (l == 0) {
            const float* Af = inMusic + (size_t)k * BAT * FEAT;
            const int ar = tid >> 4, ac = (tid & 15) * 4;
            const int apan = ac >> 5, alc = ac & 31;
            float4 aR[8]; uint4 bR[2][2];
#pragma unroll
            for (int it = 0; it < 8; ++it)
                aR[it] = *(const float4*)(Af + (size_t)(it * 16 + ar) * FEAT + ac);
#pragma unroll
            for (int it = 0; it < 2; ++it)
#pragma unroll
                for (int h = 0; h < 2; ++h)
                    bR[it][h] = *(const uint4*)(BihS + po(it * 64 + br, 0, h));
            for (int ii = 0; ii < 2; ++ii) {
                __syncthreads();
#pragma unroll
                for (int it = 0; it < 8; ++it) {
                    ushort4 pk = make_ushort4(f2bf(aR[it].x), f2bf(aR[it].y),
                                              f2bf(aR[it].z), f2bf(aR[it].w));
                    *(ushort4*)&sm.st.a[apan][(it * 16 + ar) * LDSS + alc] = pk;
                }
#pragma unroll
                for (int it = 0; it < 2; ++it)
#pragma unroll
                    for (int h = 0; h < 2; ++h)
                        *(uint4*)&sm.st.b[h][(it * 64 + br) * LDSS + bc] = bR[it][h];
                if (ii == 0) {
#pragma unroll
                    for (int it = 0; it < 8; ++it)
                        aR[it] = *(const float4*)(Af + (size_t)(it * 16 + ar) * FEAT + ac + 64);
#pragma unroll
                    for (int it = 0; it < 2; ++it)
#pragma unroll
                        for (int h = 0; h < 2; ++h)
                            bR[it][h] = *(const uint4*)(BihS + po(it * 64 + br, 64, h));
                }
                __syncthreads();
                mfma_panels();
            }
            kloop_sp(chainH + (size_t)rk * SLOTE, BhhS);
        } else {
            kloop_sp(chainH + (size_t)(k + 1) * SLOTE, BihS);
            kloop_sp(chainH + (size_t)(97 + rk) * SLOTE, BhhS);
        }

        __syncthreads();   // sG aliases staging panels; also drains prefetch tails
        size_t slotBase = (size_t)(l * 97 + k + 1) * SLOTE;
#pragma unroll 1
        for (int i = 0; i < 4; ++i) {
#pragma unroll
            for (int j = 0; j < 4; ++j)
#pragma unroll
                for (int r = 0; r < 4; ++r)
                    sm.g[wm * 16 + quad * 4 + r][wn * 64 + j * 16 + lc] = acc[i][j][r];
            __syncthreads();
            int lrow = (rl >> 4) * 64 + i * 16 + (rl & 15);
            size_t pOff = slotBase + ((size_t)tn * 128 + lrow) * 32 + ub;
            float c2v[4], h2v[4];
#pragma unroll
            for (int uu = 0; uu < 4; ++uu) {
                float4 gg = *(const float4*)&sm.g[rl][(ub + uu) * 4];
                float iv = fsig(gg.x), fv = fsig(gg.y), gv = ftanh(gg.z), ov = fsig(gg.w);
                float c2 = fv * creg[i][uu] + iv * gv;
                if (k != 0) creg[i][uu] = c2;    // filter update only for k>=1
                c2v[uu] = c2;
                h2v[uu] = ov * ftanh(c2);
            }
            // both chains: write-through agent atomics (never dirty in L2)
            cstore8(chainH + pOff,
                    pack4bf(f2bf(h2v[0]), f2bf(h2v[1]), f2bf(h2v[2]), f2bf(h2v[3])));
            cstore8(chainCb + pOff,
                    pack4bf(f2bf(c2v[0]), f2bf(c2v[1]), f2bf(c2v[2]), f2bf(c2v[3])));
            if (k == 95) {
                size_t sOff = (size_t)l * SLOTE + (size_t)lrow * HID + tn * 32 + ub;
                *(float4*)(h_std + sOff) = make_float4(h2v[0], h2v[1], h2v[2], h2v[3]);
                *(float4*)(c_std + sOff) = make_float4(c2v[0], c2v[1], c2v[2], c2v[3]);
            }
            __syncthreads();   // drains vmcnt(0) per wave: all stores at L3
        }
        // RELAXED flag store: every wave's write-through stores retired at
        // the coherence point before the barrier above -> no wbl2 needed.
        if (tid == 0)
            __hip_atomic_store((__attribute__((address_space(1))) int*)(fw(l, k + 1) + tn * 32),
                               1, __ATOMIC_RELAXED, __HIP_MEMORY_SCOPE_AGENT);
    }
}

// =====================================================================
// Phase B: GEMM+LSTM / GEMM+linear, split into two kernel names for
// rocprof attribution. Bodies identical to the round-1 gemm_b paths.
// =====================================================================
struct GArgs {
    const u16* A1; const u16* A2;
    const u16 *B1, *B2;
    const float* bias;
    const u16* c_in; u16* cout_b;
    u16* h_out;
    u16* lin_out;
    int KP1, KP2;          // panels (K/32) per seg; 0 = absent
    int as1, as2;          // A tile stride (elements)
    int mode;
};

// persistent LSTM-step GEMM: 768 blocks, tn=bx&31, 4 tm tiles each
__global__ __launch_bounds__(256, 3) void gemm_lstm(GArgs g)
{
    __shared__ u16 sA[8192], sB[8192];
    __shared__ float sG[32][132];
    const int tid = threadIdx.x;
    const int wave = tid >> 6, lane = tid & 63;
    const int wm = wave >> 1, wn = wave & 1;
    const int quad = lane >> 4, lc = lane & 15;
    const int tn = blockIdx.x & 31;
    const int tm0 = (blockIdx.x >> 5) * 4;

    for (int t = 0; t < 4; ++t) {
        const int tm = tm0 + t;
        f32x4 acc[4][4];
#pragma unroll
        for (int j = 0; j < 4; ++j) {
            float bvx = g.bias[tn * 128 + wn * 64 + j * 16 + lc];
            f32x4 bvv = {bvx, bvx, bvx, bvx};
#pragma unroll
            for (int i = 0; i < 4; ++i) acc[i][j] = bvv;
        }

        for (int seg = 0; seg < 2; ++seg) {
            const int KP = seg ? g.KP2 : g.KP1;
            if (!KP) continue;
            const u16* Ap = seg ? (g.A2 + (size_t)tm * g.as2)
                                : (g.A1 + (size_t)tm * g.as1);
            const u16* Bp = (seg ? g.B2 : g.B1) + (size_t)tn * KP * 4096;
            const int NIT = KP >> 1;
            for (int ii = 0; ii < NIT; ++ii) {
                __syncthreads();
                const u16* ga = Ap + (size_t)ii * 8192;
                const u16* gb = Bp + (size_t)ii * 8192;
#pragma unroll
                for (int c4 = 0; c4 < 4; ++c4) {
                    int ch = wave * 4 + c4;
                    gl2lds16(ga + ch * 512 + lane * 8, &sA[ch * 512]);
                    gl2lds16(gb + ch * 512 + lane * 8, &sB[ch * 512]);
                }
                __syncthreads();
#pragma unroll
                for (int p = 0; p < 2; ++p) {
                    bf16x8 aF[4], bF[4];
#pragma unroll
                    for (int i = 0; i < 4; ++i)
                        aF[i] = *(const bf16x8*)&sA[p * 4096 + (wm * 64 + i * 16 + lc) * 32 + quad * 8];
#pragma unroll
                    for (int j = 0; j < 4; ++j)
                        bF[j] = *(const bf16x8*)&sB[p * 4096 + (wn * 64 + j * 16 + lc) * 32 + quad * 8];
#pragma unroll
                    for (int i = 0; i < 4; ++i)
#pragma unroll
                        for (int j = 0; j < 4; ++j)
                            acc[i][j] = __builtin_amdgcn_mfma_f32_16x16x32_bf16(aF[i], bF[j], acc[i][j], 0, 0, 0);
                }
            }
        }

        const int rl = tid >> 3, ub = (tid & 7) * 4;
#pragma unroll 1
        for (int i = 0; i < 4; ++i) {
#pragma unroll
            for (int j = 0; j < 4; ++j)
#pragma unroll
                for (int r = 0; r < 4; ++r)
                    sG[wm * 16 + quad * 4 + r][wn * 64 + j * 16 + lc] = acc[i][j][r];
            __syncthreads();
            int lrow = (rl >> 4) * 64 + i * 16 + (rl & 15);
            size_t pOff = (size_t)tm * SLOTE + ((size_t)tn * 128 + lrow) * 32 + ub;
            ushort4 co = *(const ushort4*)(g.c_in + pOff);
            float cold[4] = {bf2f(co.x), bf2f(co.y), bf2f(co.z), bf2f(co.w)};
            float c2v[4], h2v[4];
#pragma unroll
            for (int uu = 0; uu < 4; ++uu) {
                float4 gg = *(const float4*)&sG[rl][(ub + uu) * 4];
                float iv = fsig(gg.x), fv = fsig(gg.y), gv = ftanh(gg.z), ov = fsig(gg.w);
                float c2 = fv * cold[uu] + iv * gv;
                c2v[uu] = c2;
                h2v[uu] = ov * ftanh(c2);
            }
            *(ushort4*)(g.cout_b + pOff) =
                make_ushort4(f2bf(c2v[0]), f2bf(c2v[1]), f2bf(c2v[2]), f2bf(c2v[3]));
            *(ushort4*)(g.h_out + pOff) =
                make_ushort4(f2bf(h2v[0]), f2bf(h2v[1]), f2bf(h2v[2]), f2bf(h2v[3]));
            __syncthreads();
        }
    }
}

// linear-head GEMM: grid = 96 blocks (one per sample tile), tn = 0
__global__ __launch_bounds__(256, 3) void gemm_lin(GArgs g)
{
    __shared__ u16 sA[8192], sB[8192];
    const int tid = threadIdx.x;
    const int wave = tid >> 6, lane = tid & 63;
    const int wm = wave >> 1, wn = wave & 1;
    const int quad = lane >> 4, lc = lane & 15;
    const int tm = blockIdx.x;

    f32x4 acc[4][4];
#pragma unroll
    for (int j = 0; j < 4; ++j) {
        float bvx = g.bias[wn * 64 + j * 16 + lc];
        f32x4 bvv = {bvx, bvx, bvx, bvx};
#pragma unroll
        for (int i = 0; i < 4; ++i) acc[i][j] = bvv;
    }

    const u16* Ap = g.A1 + (size_t)tm * g.as1;
    const u16* Bp = g.B1;
    const int NIT = g.KP1 >> 1;
    for (int ii = 0; ii < NIT; ++ii) {
        __syncthreads();
        const u16* ga = Ap + (size_t)ii * 8192;
        const u16* gb = Bp + (size_t)ii * 8192;
#pragma unroll
        for (int c4 = 0; c4 < 4; ++c4) {
            int ch = wave * 4 + c4;
            gl2lds16(ga + ch * 512 + lane * 8, &sA[ch * 512]);
            gl2lds16(gb + ch * 512 + lane * 8, &sB[ch * 512]);
        }
        __syncthreads();
#pragma unroll
        for (int p = 0; p < 2; ++p) {
            bf16x8 aF[4], bF[4];
#pragma unroll
            for (int i = 0; i < 4; ++i)
                aF[i] = *(const bf16x8*)&sA[p * 4096 + (wm * 64 + i * 16 + lc) * 32 + quad * 8];
#pragma unroll
            for (int j = 0; j < 4; ++j)
                bF[j] = *(const bf16x8*)&sB[p * 4096 + (wn * 64 + j * 16 + lc) * 32 + quad * 8];
#pragma unroll
            for (int i = 0; i < 4; ++i)
#pragma unroll
                for (int j = 0; j < 4; ++j)
                    acc[i][j] = __builtin_amdgcn_mfma_f32_16x16x32_bf16(aF[i], bF[j], acc[i][j], 0, 0, 0);
        }
    }

    // write pred tile in panel-major [tm][4][128][32]
#pragma unroll
    for (int i = 0; i < 4; ++i)
#pragma unroll
        for (int j = 0; j < 4; ++j)
#pragma unroll
            for (int r = 0; r < 4; ++r) {
                int grow = wm * 64 + i * 16 + quad * 4 + r;
                int gcol = wn * 64 + j * 16 + lc;
                size_t addr = (size_t)tm * PREDT + (size_t)(gcol >> 5) * 4096
                            + (size_t)grow * 32 + (gcol & 31);
                g.lin_out[addr] = f2bf(acc[i][j][r]);
            }
}

// ---- setup / epilogue kernels ----
__global__ void convert_weight(const float* __restrict__ src, u16* __restrict__ dst,
                               int kshift, int permute, int total) {
    int idx = blockIdx.x * 256 + threadIdx.x;
    if (idx >= total) return;
    int kk = idx & 31;
    int r = (idx >> 5) & 127;
    int kp = (idx >> 12) & ((1 << (kshift - 5)) - 1);
    int stripe = idx >> (7 + kshift);
    int jp = stripe * 128 + r;
    int srow = permute ? ((jp & 3) * HID + (jp >> 2)) : jp;
    dst[idx] = f2bf(src[((size_t)srow << kshift) + kp * 32 + kk]);
}

__global__ void combine_bias(const float* __restrict__ bi, const float* __restrict__ bh,
                             float* __restrict__ dst) {
    int j = blockIdx.x * 256 + threadIdx.x;  // 4096
    int s = (j & 3) * HID + (j >> 2);
    dst[j] = bi[s] + bh[s];
}

__global__ void init_state(const float* __restrict__ h0, u16* __restrict__ chainH) {
    int idx = blockIdx.x * 256 + threadIdx.x;  // 2*BAT*HID
    int l = idx >> 17;
    int r = idx & (int)(SLOTE - 1);
    int b = r >> 10, hh = r & 1023;
    size_t po = ((size_t)(hh >> 5) * 128 + b) * 32 + (hh & 31);
    chainH[(size_t)l * 97 * SLOTE + po] = f2bf(h0[idx]);
}

__global__ void init_flags(int* __restrict__ f) {
    int gid = blockIdx.x * 256 + threadIdx.x;
    if (gid >= FLAGN) return;
    int step = (gid >> 10) % 97;             // flag word stride 32 ints; 32 blocks/step
    f[gid] = ((gid & 31) == 0 && step == 0) ? 1 : 0;
}

__global__ void copy_next(const u16* __restrict__ predsb, float* __restrict__ out) {
    int idx = blockIdx.x * 256 + threadIdx.x;  // BAT*FEAT
    int b = idx >> 7, f = idx & 127;
    out[idx] = bf2f(predsb[(size_t)95 * PREDT + (size_t)(f >> 5) * 4096 + b * 32 + (f & 31)]);
}

__global__ void gather_out(const float* __restrict__ inMusic, const u16* __restrict__ predsb,
                           float* __restrict__ outM) {
    int idx = blockIdx.x * 256 + threadIdx.x;  // 96*128*128*8
    int n = idx & 7;
    int f = (idx >> 3) & 127;
    int b = (idx >> 10) & 127;
    int r = idx >> 17;
    float v = 0.0f;
    if (r < NPRED && n >= r) {
        v = inMusic[((size_t)r * BAT + b) * FEAT + f];
    } else {
        int k = r - n - 1;
        if (n < k)
            v = bf2f(predsb[(size_t)n * NSAMP * PREDT + (size_t)k * PREDT
                            + (size_t)(f >> 5) * 4096 + b * 32 + (f & 31)]);
    }
    outM[idx] = v;
}

__global__ void zero_out(float* __restrict__ o, int nmax) {
    int idx = blockIdx.x * 256 + threadIdx.x;
    if (idx < nmax) o[idx] = 0.0f;
}

extern "C" void kernel_launch(void* const* d_in, const int* in_sizes, int n_in,
                              void* d_out, int out_size, void* d_ws, size_t ws_size,
                              hipStream_t stream) {
    (void)in_sizes; (void)n_in;
    const float* inMusic = (const float*)d_in[0];
    const float* h0   = (const float*)d_in[1];
    const float* c0   = (const float*)d_in[2];
    const float* Wih0 = (const float*)d_in[3];
    const float* Whh0 = (const float*)d_in[4];
    const float* bih0 = (const float*)d_in[5];
    const float* bhh0 = (const float*)d_in[6];
    const float* Wih1 = (const float*)d_in[7];
    const float* Whh1 = (const float*)d_in[8];
    const float* bih1 = (const float*)d_in[9];
    const float* bhh1 = (const float*)d_in[10];
    const float* Wlin = (const float*)d_in[11];
    const float* blin = (const float*)d_in[12];
    float* out = (float*)d_out;

    const size_t OUT_H = (size_t)NSAMP * BAT * FEAT * NPRED;
    const size_t OUT_C = OUT_H + 2 * SLOTE;
    const size_t OUT_NEXT = OUT_C + 2 * SLOTE;

    char* ws = (char*)d_ws;
    size_t off = 0;
    auto alloc = [&](size_t bytes) {
        void* p = ws + off;
        off = (off + bytes + 255) & ~(size_t)255;
        return p;
    };
    u16* Wih0p = (u16*)alloc((size_t)GD * FEAT * 2);
    u16* Whh0p = (u16*)alloc((size_t)GD * HID * 2);
    u16* Wih1p = (u16*)alloc((size_t)GD * HID * 2);
    u16* Whh1p = (u16*)alloc((size_t)GD * HID * 2);
    u16* Wlinb = (u16*)alloc((size_t)FEAT * HID * 2);
    float* bp0 = (float*)alloc(GD * 4);
    float* bp1 = (float*)alloc(GD * 4);
    u16* chainH  = (u16*)alloc((size_t)2 * 97 * SLOTE * 2);
    u16* chainCb = (u16*)alloc((size_t)2 * 97 * SLOTE * 2);
    u16* hp2 = (u16*)alloc((size_t)2 * (size_t)NSAMP * SLOTE * 2);
    u16* predsb = (u16*)alloc((size_t)NPRED * NSAMP * PREDT * 2);
    int* flags = (int*)alloc((size_t)FLAGN * 4);

    if (off > ws_size) {
        zero_out<<<(out_size + 255) / 256, 256, 0, stream>>>(out, out_size);
        return;
    }

    convert_weight<<<(GD * FEAT + 255) / 256, 256, 0, stream>>>(Wih0, Wih0p, 7, 1, GD * FEAT);
    convert_weight<<<(GD * HID + 255) / 256, 256, 0, stream>>>(Whh0, Whh0p, 10, 1, GD * HID);
    convert_weight<<<(GD * HID + 255) / 256, 256, 0, stream>>>(Wih1, Wih1p, 10, 1, GD * HID);
    convert_weight<<<(GD * HID + 255) / 256, 256, 0, stream>>>(Whh1, Whh1p, 10, 1, GD * HID);
    convert_weight<<<(FEAT * HID + 255) / 256, 256, 0, stream>>>(Wlin, Wlinb, 10, 0, FEAT * HID);
    combine_bias<<<GD / 256, 256, 0, stream>>>(bih0, bhh0, bp0);
    combine_bias<<<GD / 256, 256, 0, stream>>>(bih1, bhh1, bp1);
    init_state<<<(int)(2 * SLOTE) / 256, 256, 0, stream>>>(h0, chainH);
    init_flags<<<(FLAGN + 255) / 256, 256, 0, stream>>>(flags);

    lstm_chain<<<64, 256, 0, stream>>>(
        inMusic, Wih0p, Whh0p, Wih1p, Whh1p, bp0, bp1, c0,
        chainH, chainCb, out + OUT_H, out + OUT_C, flags);

    auto Hs = [&](int l, int s) { return chainH + ((size_t)l * 97 + s) * SLOTE; };
    auto Cs = [&](int l, int s) { return chainCb + ((size_t)l * 97 + s) * SLOTE; };

    u16* hbuf0[2] = {Hs(0, 1), Hs(1, 1)};
    u16* hbuf1[2] = {hp2, hp2 + (size_t)NSAMP * SLOTE};
    u16* cB[2] = {Cs(0, 1), Cs(1, 1)};

    auto mkLin = [&](const u16* src, u16* dst) {
        GArgs a = {};
        a.A1 = src; a.KP1 = 32; a.as1 = (int)SLOTE; a.KP2 = 0;
        a.B1 = Wlinb; a.bias = blin;
        a.lin_out = dst; a.mode = 1;
        return a;
    };
    auto mkB = [&](int l, const u16* A1, int kp1, int as1, const u16* A2, u16* nxt) {
        GArgs a = {};
        a.A1 = A1; a.KP1 = kp1; a.as1 = as1;
        a.A2 = A2; a.KP2 = 32; a.as2 = (int)SLOTE;
        a.B1 = (l == 0) ? Wih0p : Wih1p; a.B2 = (l == 0) ? Whh0p : Whh1p;
        a.bias = (l == 0) ? bp0 : bp1;
        a.c_in = cB[l]; a.cout_b = cB[l];
        a.h_out = nxt; a.mode = 0;
        return a;
    };

    gemm_lin<<<96, 256, 0, stream>>>(mkLin(hbuf0[1], predsb));
    copy_next<<<(BAT * FEAT) / 256, 256, 0, stream>>>(predsb, out + OUT_NEXT);

    for (int n = 1; n < NPRED; ++n) {
        u16* cur0 = (n & 1) ? hbuf0[0] : hbuf1[0];
        u16* cur1 = (n & 1) ? hbuf0[1] : hbuf1[1];
        u16* nxt0 = (n & 1) ? hbuf1[0] : hbuf0[0];
        u16* nxt1 = (n & 1) ? hbuf1[1] : hbuf0[1];
        const u16* pin = predsb + (size_t)(n - 1) * NSAMP * PREDT;
        u16* pout = predsb + (size_t)n * NSAMP * PREDT;
        gemm_lstm<<<768, 256, 0, stream>>>(mkB(0, pin, 4, PREDT, cur0, nxt0));
        gemm_lstm<<<768, 256, 0, stream>>>(mkB(1, nxt0, 32, (int)SLOTE, cur1, nxt1));
        gemm_lin<<<96, 256, 0, stream>>>(mkLin(nxt1, pout));
    }

    gather_out<<<(NSAMP * BAT * FEAT * NPRED) / 256, 256, 0, stream>>>(inMusic, predsb, out);
}

// Round 4
// 15002.136 us; speedup vs baseline: 2.4421x; 1.7766x over previous
//
#include <hip/hip_runtime.h>

#define HID 1024
#define FEAT 128
#define BAT 128
#define NSAMP 96
#define NPRED 8
#define GD 4096                    // 4*HID
#define SLOTE ((size_t)BAT * HID)  // 131072 elements per 128-row state slot
#define PREDT 16384                // elements per pred tile (2 chunk-groups)
#define CHUNK 8192                 // elements per 64-K chunk-group (16KB)

typedef unsigned short u16;
typedef unsigned int u32;
typedef unsigned long long u64;
typedef short bf16x8 __attribute__((ext_vector_type(8)));
typedef float f32x4 __attribute__((ext_vector_type(4)));

__device__ inline u16 f2bf(float f) {
    unsigned u = __float_as_uint(f);
    u += 0x7FFFu + ((u >> 16) & 1u);
    return (u16)(u >> 16);
}
__device__ inline float bf2f(u16 h) { return __uint_as_float(((unsigned)h) << 16); }
__device__ inline float fsig(float x) { return 1.0f / (1.0f + __expf(-x)); }
__device__ inline float ftanh(float x) { return 1.0f - 2.0f / (__expf(2.0f * x) + 1.0f); }

// ---------------------------------------------------------------------
// Fragment-major (FM) layout: a [128 rows][K] operand is stored so that
// one 64-K chunk-group (8192 elems = 16KB) is 16 x 1KB chunks, chunk
// c = h2*8 + i*2 + p, and within a chunk lane l = kq*16 + lc holds 16B:
//   element(row = h2*64 + i*16 + lc,  k = 64*g + p*32 + kq*8 + e)
// Consequences: global_load_lds stages it as a LINEAR chunk copy (no
// ds_writes), and an MFMA wave's fragment read is base + lane*16B ->
// zero LDS bank conflicts by construction.
// ---------------------------------------------------------------------
__device__ inline size_t fmoff(int row, int kk) {
    return (size_t)(kk >> 6) * CHUNK + (size_t)(row >> 6) * 4096
         + (size_t)((row >> 4) & 3) * 1024 + (size_t)((kk >> 5) & 1) * 512
         + (size_t)((kk >> 3) & 3) * 128 + (size_t)(row & 15) * 8 + (kk & 7);
}

__device__ inline void gl2lds16(const u16* g, u16* l) {
    __builtin_amdgcn_global_load_lds(
        (const __attribute__((address_space(1))) u32*)g,
        (__attribute__((address_space(3))) u32*)l, 16, 0, 0);
}

// Write-through agent-scope relaxed atomic 8B store: acks from the
// coherence point, never dirty in any L2. Consumers (DMA/plain loads)
// are safe because every chainH line is write-once-then-read (flag
// ordered), and L2/L1 start each dispatch clean.
__device__ inline void cstore8(u16* p, u64 v) {
    __hip_atomic_store((__attribute__((address_space(1))) u64*)p, v,
                       __ATOMIC_RELAXED, __HIP_MEMORY_SCOPE_AGENT);
}

__device__ inline u64 pack4bf(u16 a, u16 b, u16 c, u16 d) {
    return (u64)a | ((u64)b << 16) | ((u64)c << 32) | ((u64)d << 48);
}

// ---- per-block flags: word (l,step,b) at ((l*97+step)*32+b)*32 ints ----
#define FLAGN (2 * 97 * 32 * 32)
__device__ inline void waitset(const int* base) {
    const int tid = threadIdx.x;
    if (tid < 64) {
        long t = 0;
        for (;;) {
            int v = (tid < 32)
                ? __hip_atomic_load(base + tid * 32, __ATOMIC_RELAXED, __HIP_MEMORY_SCOPE_AGENT)
                : 1;
            if (__all(v != 0)) break;
            __builtin_amdgcn_s_sleep(2);
            if (++t > 3000000L) break;   // bounded: fail loud (wrong answer), not hang
        }
    }
    __builtin_amdgcn_fence(__ATOMIC_ACQUIRE, "workgroup");
    __syncthreads();   // also drains vmcnt(0): pre-issued DMAs land here
}

// Phase-A LDS: 2 x (16KB A + 16KB B) double buffer = 64KB (static limit).
union SMemA {
    u16 st[2][2][CHUNK];   // [buf][0=A,1=B][elems]
    float g[32][132];
};

// =====================================================================
// Phase A: persistent 2-layer filter chain. 64 blocks: b<32 -> L0 panel
// b; b>=32 -> L1. All operands FM-layout; staging = pure global_load_lds
// DMA (zero ds_writes, zero read conflicts). K-loop = T3 2-phase
// template: stage(next buf) || MFMA(cur buf); vmcnt(0)+barrier per chunk.
// =====================================================================
__global__ __launch_bounds__(256, 1) void lstm_chain(
    const u16* __restrict__ inb,
    const u16* __restrict__ Wih0p, const u16* __restrict__ Whh0p,
    const u16* __restrict__ Wih1p, const u16* __restrict__ Whh1p,
    const float* __restrict__ bp0, const float* __restrict__ bp1,
    const float* __restrict__ c0,
    u16* __restrict__ chainH, u16* __restrict__ chainCb,
    float* __restrict__ h_std, float* __restrict__ c_std,
    int* __restrict__ flags)
{
    __shared__ SMemA sm;
    const int blk = blockIdx.x;
    const int l = blk >> 5, tn = blk & 31;
    const int tid = threadIdx.x;
    const int wave = tid >> 6, lane = tid & 63;
    const int wm = wave >> 1, wn = wave & 1;
    const int quad = lane >> 4, lc = lane & 15;
    const int rl = tid >> 3, ub = (tid & 7) * 4;

    const u16* BihS = (l ? Wih1p : Wih0p) + (size_t)tn * 128 * (l ? HID : FEAT);
    const u16* BhhS = (l ? Whh1p : Whh0p) + (size_t)tn * 128 * HID;
    const float* bias = l ? bp1 : bp0;
    auto fw = [&](int ll, int s) { return flags + ((size_t)(ll * 97 + s) * 32) * 32; };

    float creg[4][4];
#pragma unroll
    for (int i = 0; i < 4; ++i) {
        int lrow = (rl >> 4) * 64 + i * 16 + (rl & 15);
        float4 c4 = *(const float4*)(c0 + (size_t)l * SLOTE + (size_t)lrow * HID + tn * 32 + ub);
        creg[i][0] = c4.x; creg[i][1] = c4.y; creg[i][2] = c4.z; creg[i][3] = c4.w;
    }
    float bv[4];
#pragma unroll
    for (int j = 0; j < 4; ++j) bv[j] = bias[tn * 128 + wn * 64 + j * 16 + lc];

    const int frA = wm * 4096 + (quad * 16 + lc) * 8;   // + i*1024 + p*512
    const int frB = wn * 4096 + (quad * 16 + lc) * 8;

    for (int k = 0; k < NSAMP; ++k) {
        const int rk = (k <= 1) ? 0 : k;

        const u16 *A0, *B0, *A1, *B1; int n0, NC;
        if (l == 0) {
            A0 = inb + (size_t)k * PREDT;             B0 = BihS; n0 = 2;
            A1 = chainH + (size_t)rk * SLOTE;         B1 = BhhS; NC = 18;
        } else {
            A0 = chainH + (size_t)(k + 1) * SLOTE;    B0 = BihS; n0 = 16;
            A1 = chainH + (size_t)(97 + rk) * SLOTE;  B1 = BhhS; NC = 32;
        }
        auto issue = [&](int q, int tb) {
            const u16 *ga, *gb;
            if (q < n0) { ga = A0 + (size_t)q * CHUNK;        gb = B0 + (size_t)q * CHUNK; }
            else        { ga = A1 + (size_t)(q - n0) * CHUNK; gb = B1 + (size_t)(q - n0) * CHUNK; }
            u16* la = sm.st[tb][0];
            u16* lb = sm.st[tb][1];
#pragma unroll
            for (int c = 0; c < 4; ++c) {
                int ch = wave * 4 + c;
                gl2lds16(ga + ch * 512 + lane * 8, la + ch * 512);
                gl2lds16(gb + ch * 512 + lane * 8, lb + ch * 512);
            }
        };

        // pre-issue flag-free chunk 0 so its latency hides under the spin;
        // waitset's internal __syncthreads (vmcnt(0) drain) lands it.
        if (l == 0) {
            issue(0, 0);
            waitset(fw(0, rk));
        } else {
            waitset(fw(0, k + 1));
            issue(0, 0);                 // slot k+1: flag held
            waitset(fw(1, rk));
        }

        f32x4 acc[4][4];
#pragma unroll
        for (int j = 0; j < 4; ++j) {
            f32x4 bvv = {bv[j], bv[j], bv[j], bv[j]};
#pragma unroll
            for (int i = 0; i < 4; ++i) acc[i][j] = bvv;
        }

        int buf = 0;
        for (int q = 0; q < NC; ++q) {
            if (q + 1 < NC) issue(q + 1, buf ^ 1);   // overlaps MFMA below
            const u16* la = sm.st[buf][0];
            const u16* lb = sm.st[buf][1];
#pragma unroll
            for (int p = 0; p < 2; ++p) {
                bf16x8 aF[4], bF[4];
#pragma unroll
                for (int i = 0; i < 4; ++i)
                    aF[i] = *(const bf16x8*)&la[frA + i * 1024 + p * 512];
#pragma unroll
                for (int j = 0; j < 4; ++j)
                    bF[j] = *(const bf16x8*)&lb[frB + j * 1024 + p * 512];
#pragma unroll
                for (int i = 0; i < 4; ++i)
#pragma unroll
                    for (int j = 0; j < 4; ++j)
                        acc[i][j] = __builtin_amdgcn_mfma_f32_16x16x32_bf16(aF[i], bF[j], acc[i][j], 0, 0, 0);
            }
            asm volatile("s_waitcnt vmcnt(0)" ::: "memory");  // next buf landed
            __builtin_amdgcn_s_barrier();                     // all waves landed + done reading
            __builtin_amdgcn_sched_barrier(0);
            buf ^= 1;
        }

        __syncthreads();   // sG aliases staging buffers
        size_t slotBase = (size_t)(l * 97 + k + 1) * SLOTE;
#pragma unroll 1
        for (int i = 0; i < 4; ++i) {
#pragma unroll
            for (int j = 0; j < 4; ++j)
#pragma unroll
                for (int r = 0; r < 4; ++r)
                    sm.g[wm * 16 + quad * 4 + r][wn * 64 + j * 16 + lc] = acc[i][j][r];
            __syncthreads();
            int lrow = (rl >> 4) * 64 + i * 16 + (rl & 15);
            float c2v[4], h2v[4];
#pragma unroll
            for (int uu = 0; uu < 4; ++uu) {
                float4 gg = *(const float4*)&sm.g[rl][(ub + uu) * 4];
                float iv = fsig(gg.x), fv = fsig(gg.y), gv = ftanh(gg.z), ov = fsig(gg.w);
                float c2 = fv * creg[i][uu] + iv * gv;
                if (k != 0) creg[i][uu] = c2;    // filter update only for k>=1
                c2v[uu] = c2;
                h2v[uu] = ov * ftanh(c2);
            }
            // h chain: FM layout, write-through agent store
            cstore8(chainH + slotBase + fmoff(lrow, tn * 32 + ub),
                    pack4bf(f2bf(h2v[0]), f2bf(h2v[1]), f2bf(h2v[2]), f2bf(h2v[3])));
            // c chain: consumed only by later dispatches -> plain store, old layout
            size_t pOff = slotBase + ((size_t)tn * 128 + lrow) * 32 + ub;
            *(ushort4*)(chainCb + pOff) =
                make_ushort4(f2bf(c2v[0]), f2bf(c2v[1]), f2bf(c2v[2]), f2bf(c2v[3]));
            if (k == 95) {
                size_t sOff = (size_t)l * SLOTE + (size_t)lrow * HID + tn * 32 + ub;
                *(float4*)(h_std + sOff) = make_float4(h2v[0], h2v[1], h2v[2], h2v[3]);
                *(float4*)(c_std + sOff) = make_float4(c2v[0], c2v[1], c2v[2], c2v[3]);
            }
            __syncthreads();   // drains vmcnt(0): all stores at coherence point
        }
        if (tid == 0)
            __hip_atomic_store((__attribute__((address_space(1))) int*)(fw(l, k + 1) + tn * 32),
                               1, __ATOMIC_RELAXED, __HIP_MEMORY_SCOPE_AGENT);
    }
}

// =====================================================================
// Phase B: GEMM+LSTM / GEMM+linear. Staging unchanged (FM global ==
// linear chunk copy); fragment reads now conflict-free FM; h/pred
// outputs written FM.
// =====================================================================
struct GArgs {
    const u16* A1; const u16* A2;
    const u16 *B1, *B2;
    const float* bias;
    const u16* c_in; u16* cout_b;
    u16* h_out;
    u16* lin_out;
    int KP1, KP2;          // panels (K/32) per seg; 0 = absent
    int as1, as2;          // A tile stride (elements)
    int mode;
};

__global__ __launch_bounds__(256, 3) void gemm_lstm(GArgs g)
{
    __shared__ u16 sA[8192], sB[8192];
    __shared__ float sG[32][132];
    const int tid = threadIdx.x;
    const int wave = tid >> 6, lane = tid & 63;
    const int wm = wave >> 1, wn = wave & 1;
    const int quad = lane >> 4, lc = lane & 15;
    const int tn = blockIdx.x & 31;
    const int tm0 = (blockIdx.x >> 5) * 4;
    const int frA = wm * 4096 + (quad * 16 + lc) * 8;
    const int frB = wn * 4096 + (quad * 16 + lc) * 8;

    for (int t = 0; t < 4; ++t) {
        const int tm = tm0 + t;
        f32x4 acc[4][4];
#pragma unroll
        for (int j = 0; j < 4; ++j) {
            float bvx = g.bias[tn * 128 + wn * 64 + j * 16 + lc];
            f32x4 bvv = {bvx, bvx, bvx, bvx};
#pragma unroll
            for (int i = 0; i < 4; ++i) acc[i][j] = bvv;
        }

        for (int seg = 0; seg < 2; ++seg) {
            const int KP = seg ? g.KP2 : g.KP1;
            if (!KP) continue;
            const u16* Ap = seg ? (g.A2 + (size_t)tm * g.as2)
                                : (g.A1 + (size_t)tm * g.as1);
            const u16* Bp = (seg ? g.B2 : g.B1) + (size_t)tn * KP * 4096;
            const int NIT = KP >> 1;
            for (int ii = 0; ii < NIT; ++ii) {
                __syncthreads();
                const u16* ga = Ap + (size_t)ii * CHUNK;
                const u16* gb = Bp + (size_t)ii * CHUNK;
#pragma unroll
                for (int c4 = 0; c4 < 4; ++c4) {
                    int ch = wave * 4 + c4;
                    gl2lds16(ga + ch * 512 + lane * 8, &sA[ch * 512]);
                    gl2lds16(gb + ch * 512 + lane * 8, &sB[ch * 512]);
                }
                __syncthreads();
#pragma unroll
                for (int p = 0; p < 2; ++p) {
                    bf16x8 aF[4], bF[4];
#pragma unroll
                    for (int i = 0; i < 4; ++i)
                        aF[i] = *(const bf16x8*)&sA[frA + i * 1024 + p * 512];
#pragma unroll
                    for (int j = 0; j < 4; ++j)
                        bF[j] = *(const bf16x8*)&sB[frB + j * 1024 + p * 512];
#pragma unroll
                    for (int i = 0; i < 4; ++i)
#pragma unroll
                        for (int j = 0; j < 4; ++j)
                            acc[i][j] = __builtin_amdgcn_mfma_f32_16x16x32_bf16(aF[i], bF[j], acc[i][j], 0, 0, 0);
                }
            }
        }

        const int rl = tid >> 3, ub = (tid & 7) * 4;
#pragma unroll 1
        for (int i = 0; i < 4; ++i) {
#pragma unroll
            for (int j = 0; j < 4; ++j)
#pragma unroll
                for (int r = 0; r < 4; ++r)
                    sG[wm * 16 + quad * 4 + r][wn * 64 + j * 16 + lc] = acc[i][j][r];
            __syncthreads();
            int lrow = (rl >> 4) * 64 + i * 16 + (rl & 15);
            size_t pOff = (size_t)tm * SLOTE + ((size_t)tn * 128 + lrow) * 32 + ub;
            ushort4 co = *(const ushort4*)(g.c_in + pOff);
            float cold[4] = {bf2f(co.x), bf2f(co.y), bf2f(co.z), bf2f(co.w)};
            float c2v[4], h2v[4];
#pragma unroll
            for (int uu = 0; uu < 4; ++uu) {
                float4 gg = *(const float4*)&sG[rl][(ub + uu) * 4];
                float iv = fsig(gg.x), fv = fsig(gg.y), gv = ftanh(gg.z), ov = fsig(gg.w);
                float c2 = fv * cold[uu] + iv * gv;
                c2v[uu] = c2;
                h2v[uu] = ov * ftanh(c2);
            }
            *(ushort4*)(g.cout_b + pOff) =
                make_ushort4(f2bf(c2v[0]), f2bf(c2v[1]), f2bf(c2v[2]), f2bf(c2v[3]));
            *(ushort4*)(g.h_out + (size_t)tm * SLOTE + fmoff(lrow, tn * 32 + ub)) =
                make_ushort4(f2bf(h2v[0]), f2bf(h2v[1]), f2bf(h2v[2]), f2bf(h2v[3]));
            __syncthreads();
        }
    }
}

__global__ __launch_bounds__(256, 3) void gemm_lin(GArgs g)
{
    __shared__ u16 sA[8192], sB[8192];
    const int tid = threadIdx.x;
    const int wave = tid >> 6, lane = tid & 63;
    const int wm = wave >> 1, wn = wave & 1;
    const int quad = lane >> 4, lc = lane & 15;
    const int tm = blockIdx.x;
    const int frA = wm * 4096 + (quad * 16 + lc) * 8;
    const int frB = wn * 4096 + (quad * 16 + lc) * 8;

    f32x4 acc[4][4];
#pragma unroll
    for (int j = 0; j < 4; ++j) {
        float bvx = g.bias[wn * 64 + j * 16 + lc];
        f32x4 bvv = {bvx, bvx, bvx, bvx};
#pragma unroll
        for (int i = 0; i < 4; ++i) acc[i][j] = bvv;
    }

    const u16* Ap = g.A1 + (size_t)tm * g.as1;
    const u16* Bp = g.B1;
    const int NIT = g.KP1 >> 1;
    for (int ii = 0; ii < NIT; ++ii) {
        __syncthreads();
        const u16* ga = Ap + (size_t)ii * CHUNK;
        const u16* gb = Bp + (size_t)ii * CHUNK;
#pragma unroll
        for (int c4 = 0; c4 < 4; ++c4) {
            int ch = wave * 4 + c4;
            gl2lds16(ga + ch * 512 + lane * 8, &sA[ch * 512]);
            gl2lds16(gb + ch * 512 + lane * 8, &sB[ch * 512]);
        }
        __syncthreads();
#pragma unroll
        for (int p = 0; p < 2; ++p) {
            bf16x8 aF[4], bF[4];
#pragma unroll
            for (int i = 0; i < 4; ++i)
                aF[i] = *(const bf16x8*)&sA[frA + i * 1024 + p * 512];
#pragma unroll
            for (int j = 0; j < 4; ++j)
                bF[j] = *(const bf16x8*)&sB[frB + j * 1024 + p * 512];
#pragma unroll
            for (int i = 0; i < 4; ++i)
#pragma unroll
                for (int j = 0; j < 4; ++j)
                    acc[i][j] = __builtin_amdgcn_mfma_f32_16x16x32_bf16(aF[i], bF[j], acc[i][j], 0, 0, 0);
        }
    }

    // pred tile in FM layout
#pragma unroll
    for (int i = 0; i < 4; ++i)
#pragma unroll
        for (int j = 0; j < 4; ++j)
#pragma unroll
            for (int r = 0; r < 4; ++r) {
                int grow = wm * 64 + i * 16 + quad * 4 + r;
                int gcol = wn * 64 + j * 16 + lc;
                g.lin_out[(size_t)tm * PREDT + fmoff(grow, gcol)] = f2bf(acc[i][j][r]);
            }
}

// ---- setup / epilogue kernels ----
__global__ void convert_weight(const float* __restrict__ src, u16* __restrict__ dst,
                               int kshift, int permute, int total) {
    int idx = blockIdx.x * 256 + threadIdx.x;
    if (idx >= total) return;
    const int K = 1 << kshift;
    int kk = idx & (K - 1);
    int rr = (idx >> kshift) & 127;
    int s = idx >> (kshift + 7);
    int jp = s * 128 + rr;
    int srow = permute ? ((jp & 3) * HID + (jp >> 2)) : jp;
    dst[((size_t)s << (kshift + 7)) + fmoff(rr, kk)] =
        f2bf(src[((size_t)srow << kshift) + kk]);
}

__global__ void conv_input(const float* __restrict__ in, u16* __restrict__ inb) {
    int idx = blockIdx.x * 256 + threadIdx.x;  // 96*128*128
    int f = idx & 127;
    int b = (idx >> 7) & 127;
    int k = idx >> 14;
    inb[(size_t)k * PREDT + fmoff(b, f)] = f2bf(in[idx]);
}

__global__ void combine_bias(const float* __restrict__ bi, const float* __restrict__ bh,
                             float* __restrict__ dst) {
    int j = blockIdx.x * 256 + threadIdx.x;  // 4096
    int s = (j & 3) * HID + (j >> 2);
    dst[j] = bi[s] + bh[s];
}

__global__ void init_state(const float* __restrict__ h0, u16* __restrict__ chainH) {
    int idx = blockIdx.x * 256 + threadIdx.x;  // 2*BAT*HID
    int l = idx >> 17;
    int r = idx & (int)(SLOTE - 1);
    int b = r >> 10, hh = r & 1023;
    chainH[(size_t)l * 97 * SLOTE + fmoff(b, hh)] = f2bf(h0[idx]);
}

__global__ void init_flags(int* __restrict__ f) {
    int gid = blockIdx.x * 256 + threadIdx.x;
    if (gid >= FLAGN) return;
    int step = (gid >> 10) % 97;             // flag word stride 32 ints; 32 blocks/step
    f[gid] = ((gid & 31) == 0 && step == 0) ? 1 : 0;
}

__global__ void copy_next(const u16* __restrict__ predsb, float* __restrict__ out) {
    int idx = blockIdx.x * 256 + threadIdx.x;  // BAT*FEAT
    int b = idx >> 7, f = idx & 127;
    out[idx] = bf2f(predsb[(size_t)95 * PREDT + fmoff(b, f)]);
}

__global__ void gather_out(const float* __restrict__ inMusic, const u16* __restrict__ predsb,
                           float* __restrict__ outM) {
    int idx = blockIdx.x * 256 + threadIdx.x;  // 96*128*128*8
    int n = idx & 7;
    int f = (idx >> 3) & 127;
    int b = (idx >> 10) & 127;
    int r = idx >> 17;
    float v = 0.0f;
    if (r < NPRED && n >= r) {
        v = inMusic[((size_t)r * BAT + b) * FEAT + f];
    } else {
        int k = r - n - 1;
        if (n < k)
            v = bf2f(predsb[((size_t)n * NSAMP + k) * PREDT + fmoff(b, f)]);
    }
    outM[idx] = v;
}

__global__ void zero_out(float* __restrict__ o, int nmax) {
    int idx = blockIdx.x * 256 + threadIdx.x;
    if (idx < nmax) o[idx] = 0.0f;
}

extern "C" void kernel_launch(void* const* d_in, const int* in_sizes, int n_in,
                              void* d_out, int out_size, void* d_ws, size_t ws_size,
                              hipStream_t stream) {
    (void)in_sizes; (void)n_in;
    const float* inMusic = (const float*)d_in[0];
    const float* h0   = (const float*)d_in[1];
    const float* c0   = (const float*)d_in[2];
    const float* Wih0 = (const float*)d_in[3];
    const float* Whh0 = (const float*)d_in[4];
    const float* bih0 = (const float*)d_in[5];
    const float* bhh0 = (const float*)d_in[6];
    const float* Wih1 = (const float*)d_in[7];
    const float* Whh1 = (const float*)d_in[8];
    const float* bih1 = (const float*)d_in[9];
    const float* bhh1 = (const float*)d_in[10];
    const float* Wlin = (const float*)d_in[11];
    const float* blin = (const float*)d_in[12];
    float* out = (float*)d_out;

    const size_t OUT_H = (size_t)NSAMP * BAT * FEAT * NPRED;
    const size_t OUT_C = OUT_H + 2 * SLOTE;
    const size_t OUT_NEXT = OUT_C + 2 * SLOTE;

    char* ws = (char*)d_ws;
    size_t off = 0;
    auto alloc = [&](size_t bytes) {
        void* p = ws + off;
        off = (off + bytes + 255) & ~(size_t)255;
        return p;
    };
    u16* Wih0p = (u16*)alloc((size_t)GD * FEAT * 2);
    u16* Whh0p = (u16*)alloc((size_t)GD * HID * 2);
    u16* Wih1p = (u16*)alloc((size_t)GD * HID * 2);
    u16* Whh1p = (u16*)alloc((size_t)GD * HID * 2);
    u16* Wlinb = (u16*)alloc((size_t)FEAT * HID * 2);
    float* bp0 = (float*)alloc(GD * 4);
    float* bp1 = (float*)alloc(GD * 4);
    u16* chainH  = (u16*)alloc((size_t)2 * 97 * SLOTE * 2);
    u16* chainCb = (u16*)alloc((size_t)2 * 97 * SLOTE * 2);
    u16* hp2 = (u16*)alloc((size_t)2 * (size_t)NSAMP * SLOTE * 2);
    u16* predsb = (u16*)alloc((size_t)NPRED * NSAMP * PREDT * 2);
    u16* inb = (u16*)alloc((size_t)NSAMP * PREDT * 2);
    int* flags = (int*)alloc((size_t)FLAGN * 4);

    if (off > ws_size) {
        zero_out<<<(out_size + 255) / 256, 256, 0, stream>>>(out, out_size);
        return;
    }

    convert_weight<<<(GD * FEAT + 255) / 256, 256, 0, stream>>>(Wih0, Wih0p, 7, 1, GD * FEAT);
    convert_weight<<<(GD * HID + 255) / 256, 256, 0, stream>>>(Whh0, Whh0p, 10, 1, GD * HID);
    convert_weight<<<(GD * HID + 255) / 256, 256, 0, stream>>>(Wih1, Wih1p, 10, 1, GD * HID);
    convert_weight<<<(GD * HID + 255) / 256, 256, 0, stream>>>(Whh1, Whh1p, 10, 1, GD * HID);
    convert_weight<<<(FEAT * HID + 255) / 256, 256, 0, stream>>>(Wlin, Wlinb, 10, 0, FEAT * HID);
    conv_input<<<(NSAMP * BAT * FEAT) / 256, 256, 0, stream>>>(inMusic, inb);
    combine_bias<<<GD / 256, 256, 0, stream>>>(bih0, bhh0, bp0);
    combine_bias<<<GD / 256, 256, 0, stream>>>(bih1, bhh1, bp1);
    init_state<<<(int)(2 * SLOTE) / 256, 256, 0, stream>>>(h0, chainH);
    init_flags<<<(FLAGN + 255) / 256, 256, 0, stream>>>(flags);

    lstm_chain<<<64, 256, 0, stream>>>(
        inb, Wih0p, Whh0p, Wih1p, Whh1p, bp0, bp1, c0,
        chainH, chainCb, out + OUT_H, out + OUT_C, flags);

    auto Hs = [&](int l, int s) { return chainH + ((size_t)l * 97 + s) * SLOTE; };
    auto Cs = [&](int l, int s) { return chainCb + ((size_t)l * 97 + s) * SLOTE; };

    u16* hbuf0[2] = {Hs(0, 1), Hs(1, 1)};
    u16* hbuf1[2] = {hp2, hp2 + (size_t)NSAMP * SLOTE};
    u16* cB[2] = {Cs(0, 1), Cs(1, 1)};

    auto mkLin = [&](const u16* src, u16* dst) {
        GArgs a = {};
        a.A1 = src; a.KP1 = 32; a.as1 = (int)SLOTE; a.KP2 = 0;
        a.B1 = Wlinb; a.bias = blin;
        a.lin_out = dst; a.mode = 1;
        return a;
    };
    auto mkB = [&](int l, const u16* A1, int kp1, int as1, const u16* A2, u16* nxt) {
        GArgs a = {};
        a.A1 = A1; a.KP1 = kp1; a.as1 = as1;
        a.A2 = A2; a.KP2 = 32; a.as2 = (int)SLOTE;
        a.B1 = (l == 0) ? Wih0p : Wih1p; a.B2 = (l == 0) ? Whh0p : Whh1p;
        a.bias = (l == 0) ? bp0 : bp1;
        a.c_in = cB[l]; a.cout_b = cB[l];
        a.h_out = nxt; a.mode = 0;
        return a;
    };

    gemm_lin<<<96, 256, 0, stream>>>(mkLin(hbuf0[1], predsb));
    copy_next<<<(BAT * FEAT) / 256, 256, 0, stream>>>(predsb, out + OUT_NEXT);

    for (int n = 1; n < NPRED; ++n) {
        u16* cur0 = (n & 1) ? hbuf0[0] : hbuf1[0];
        u16* cur1 = (n & 1) ? hbuf0[1] : hbuf1[1];
        u16* nxt0 = (n & 1) ? hbuf1[0] : hbuf0[0];
        u16* nxt1 = (n & 1) ? hbuf1[1] : hbuf0[1];
        const u16* pin = predsb + (size_t)(n - 1) * NSAMP * PREDT;
        u16* pout = predsb + (size_t)n * NSAMP * PREDT;
        gemm_lstm<<<768, 256, 0, stream>>>(mkB(0, pin, 4, PREDT, cur0, nxt0));
        gemm_lstm<<<768, 256, 0, stream>>>(mkB(1, nxt0, 32, (int)SLOTE, cur1, nxt1));
        gemm_lin<<<96, 256, 0, stream>>>(mkLin(nxt1, pout));
    }

    gather_out<<<(NSAMP * BAT * FEAT * NPRED) / 256, 256, 0, stream>>>(inMusic, predsb, out);
}

// Round 5
// 7567.154 us; speedup vs baseline: 4.8416x; 1.9825x over previous
//
#include <hip/hip_runtime.h>

#define HID 1024
#define FEAT 128
#define BAT 128
#define NSAMP 96
#define NPRED 8
#define GD 4096                    // 4*HID
#define SLOTE ((size_t)BAT * HID)  // 131072 elements per 128-row state slot
#define PREDT 16384                // elements per pred tile (2 chunk-groups)
#define CHUNK 8192                 // elements per 64-K chunk-group (16KB)

typedef unsigned short u16;
typedef unsigned int u32;
typedef unsigned long long u64;
typedef short bf16x8 __attribute__((ext_vector_type(8)));
typedef float f32x4 __attribute__((ext_vector_type(4)));

__device__ inline u16 f2bf(float f) {
    unsigned u = __float_as_uint(f);
    u += 0x7FFFu + ((u >> 16) & 1u);
    return (u16)(u >> 16);
}
__device__ inline float bf2f(u16 h) { return __uint_as_float(((unsigned)h) << 16); }
__device__ inline float fsig(float x) { return 1.0f / (1.0f + __expf(-x)); }
__device__ inline float ftanh(float x) { return 1.0f - 2.0f / (__expf(2.0f * x) + 1.0f); }

// ---------------------------------------------------------------------
// Fragment-major (FM) layout: a [128 rows][K] operand is stored so that
// one 64-K chunk-group (8192 elems = 16KB) is 16 x 1KB chunks, chunk
// c = h2*8 + i*2 + p, and within a chunk lane l = kq*16 + lc holds 16B:
//   element(row = h2*64 + i*16 + lc,  k = 64*g + p*32 + kq*8 + e)
// Consequences: global_load_lds stages it as a LINEAR chunk copy (no
// ds_writes), and an MFMA wave's fragment read is base + lane*16B ->
// zero LDS bank conflicts by construction.
// ---------------------------------------------------------------------
__device__ inline size_t fmoff(int row, int kk) {
    return (size_t)(kk >> 6) * CHUNK + (size_t)(row >> 6) * 4096
         + (size_t)((row >> 4) & 3) * 1024 + (size_t)((kk >> 5) & 1) * 512
         + (size_t)((kk >> 3) & 3) * 128 + (size_t)(row & 15) * 8 + (kk & 7);
}

__device__ inline void gl2lds16(const u16* g, u16* l) {
    __builtin_amdgcn_global_load_lds(
        (const __attribute__((address_space(1))) u32*)g,
        (__attribute__((address_space(3))) u32*)l, 16, 0, 0);
}

// Write-through agent-scope relaxed atomic 8B store: acks from the
// coherence point, never dirty in any L2.
__device__ inline void cstore8(u16* p, u64 v) {
    __hip_atomic_store((__attribute__((address_space(1))) u64*)p, v,
                       __ATOMIC_RELAXED, __HIP_MEMORY_SCOPE_AGENT);
}

__device__ inline u64 pack4bf(u16 a, u16 b, u16 c, u16 d) {
    return (u64)a | ((u64)b << 16) | ((u64)c << 32) | ((u64)d << 48);
}

// ---- per-block flags: word (l,step,b) at ((l*97+step)*32+b)*32 ints ----
#define FLAGN (2 * 97 * 32 * 32)
__device__ inline void waitset(const int* base) {
    const int tid = threadIdx.x;
    if (tid < 64) {
        long t = 0;
        for (;;) {
            int v = (tid < 32)
                ? __hip_atomic_load(base + tid * 32, __ATOMIC_RELAXED, __HIP_MEMORY_SCOPE_AGENT)
                : 1;
            if (__all(v != 0)) break;
            __builtin_amdgcn_s_sleep(2);
            if (++t > 3000000L) break;   // bounded: fail loud (wrong answer), not hang
        }
    }
    __builtin_amdgcn_fence(__ATOMIC_ACQUIRE, "workgroup");
    __syncthreads();   // also drains vmcnt(0): pre-issued DMAs land here
}

// Phase-A LDS: 2 x (16KB A + 16KB B) double buffer = 64KB (static limit).
union SMemA {
    u16 st[2][2][CHUNK];   // [buf][0=A,1=B][elems]
    float g[32][132];
};

// =====================================================================
// Phase A: persistent 2-layer filter chain (unchanged from round 4:
// 3.44ms, conflicts 9.4e6). 64 blocks: b<32 -> L0 panel b; b>=32 -> L1.
// =====================================================================
__global__ __launch_bounds__(256, 1) void lstm_chain(
    const u16* __restrict__ inb,
    const u16* __restrict__ Wih0p, const u16* __restrict__ Whh0p,
    const u16* __restrict__ Wih1p, const u16* __restrict__ Whh1p,
    const float* __restrict__ bp0, const float* __restrict__ bp1,
    const float* __restrict__ c0,
    u16* __restrict__ chainH, u16* __restrict__ chainCb,
    float* __restrict__ h_std, float* __restrict__ c_std,
    int* __restrict__ flags)
{
    __shared__ SMemA sm;
    const int blk = blockIdx.x;
    const int l = blk >> 5, tn = blk & 31;
    const int tid = threadIdx.x;
    const int wave = tid >> 6, lane = tid & 63;
    const int wm = wave >> 1, wn = wave & 1;
    const int quad = lane >> 4, lc = lane & 15;
    const int rl = tid >> 3, ub = (tid & 7) * 4;

    const u16* BihS = (l ? Wih1p : Wih0p) + (size_t)tn * 128 * (l ? HID : FEAT);
    const u16* BhhS = (l ? Whh1p : Whh0p) + (size_t)tn * 128 * HID;
    const float* bias = l ? bp1 : bp0;
    auto fw = [&](int ll, int s) { return flags + ((size_t)(ll * 97 + s) * 32) * 32; };

    float creg[4][4];
#pragma unroll
    for (int i = 0; i < 4; ++i) {
        int lrow = (rl >> 4) * 64 + i * 16 + (rl & 15);
        float4 c4 = *(const float4*)(c0 + (size_t)l * SLOTE + (size_t)lrow * HID + tn * 32 + ub);
        creg[i][0] = c4.x; creg[i][1] = c4.y; creg[i][2] = c4.z; creg[i][3] = c4.w;
    }
    float bv[4];
#pragma unroll
    for (int j = 0; j < 4; ++j) bv[j] = bias[tn * 128 + wn * 64 + j * 16 + lc];

    const int frA = wm * 4096 + (quad * 16 + lc) * 8;   // + i*1024 + p*512
    const int frB = wn * 4096 + (quad * 16 + lc) * 8;

    for (int k = 0; k < NSAMP; ++k) {
        const int rk = (k <= 1) ? 0 : k;

        const u16 *A0, *B0, *A1, *B1; int n0, NC;
        if (l == 0) {
            A0 = inb + (size_t)k * PREDT;             B0 = BihS; n0 = 2;
            A1 = chainH + (size_t)rk * SLOTE;         B1 = BhhS; NC = 18;
        } else {
            A0 = chainH + (size_t)(k + 1) * SLOTE;    B0 = BihS; n0 = 16;
            A1 = chainH + (size_t)(97 + rk) * SLOTE;  B1 = BhhS; NC = 32;
        }
        auto issue = [&](int q, int tb) {
            const u16 *ga, *gb;
            if (q < n0) { ga = A0 + (size_t)q * CHUNK;        gb = B0 + (size_t)q * CHUNK; }
            else        { ga = A1 + (size_t)(q - n0) * CHUNK; gb = B1 + (size_t)(q - n0) * CHUNK; }
            u16* la = sm.st[tb][0];
            u16* lb = sm.st[tb][1];
#pragma unroll
            for (int c = 0; c < 4; ++c) {
                int ch = wave * 4 + c;
                gl2lds16(ga + ch * 512 + lane * 8, la + ch * 512);
                gl2lds16(gb + ch * 512 + lane * 8, lb + ch * 512);
            }
        };

        if (l == 0) {
            issue(0, 0);
            waitset(fw(0, rk));
        } else {
            waitset(fw(0, k + 1));
            issue(0, 0);                 // slot k+1: flag held
            waitset(fw(1, rk));
        }

        f32x4 acc[4][4];
#pragma unroll
        for (int j = 0; j < 4; ++j) {
            f32x4 bvv = {bv[j], bv[j], bv[j], bv[j]};
#pragma unroll
            for (int i = 0; i < 4; ++i) acc[i][j] = bvv;
        }

        int buf = 0;
        for (int q = 0; q < NC; ++q) {
            if (q + 1 < NC) issue(q + 1, buf ^ 1);   // overlaps MFMA below
            const u16* la = sm.st[buf][0];
            const u16* lb = sm.st[buf][1];
#pragma unroll
            for (int p = 0; p < 2; ++p) {
                bf16x8 aF[4], bF[4];
#pragma unroll
                for (int i = 0; i < 4; ++i)
                    aF[i] = *(const bf16x8*)&la[frA + i * 1024 + p * 512];
#pragma unroll
                for (int j = 0; j < 4; ++j)
                    bF[j] = *(const bf16x8*)&lb[frB + j * 1024 + p * 512];
#pragma unroll
                for (int i = 0; i < 4; ++i)
#pragma unroll
                    for (int j = 0; j < 4; ++j)
                        acc[i][j] = __builtin_amdgcn_mfma_f32_16x16x32_bf16(aF[i], bF[j], acc[i][j], 0, 0, 0);
            }
            asm volatile("s_waitcnt vmcnt(0)" ::: "memory");  // next buf landed
            __builtin_amdgcn_s_barrier();                     // all waves landed + done reading
            __builtin_amdgcn_sched_barrier(0);
            buf ^= 1;
        }

        __syncthreads();   // sG aliases staging buffers
        size_t slotBase = (size_t)(l * 97 + k + 1) * SLOTE;
#pragma unroll 1
        for (int i = 0; i < 4; ++i) {
#pragma unroll
            for (int j = 0; j < 4; ++j)
#pragma unroll
                for (int r = 0; r < 4; ++r)
                    sm.g[wm * 16 + quad * 4 + r][wn * 64 + j * 16 + lc] = acc[i][j][r];
            __syncthreads();
            int lrow = (rl >> 4) * 64 + i * 16 + (rl & 15);
            float c2v[4], h2v[4];
#pragma unroll
            for (int uu = 0; uu < 4; ++uu) {
                float4 gg = *(const float4*)&sm.g[rl][(ub + uu) * 4];
                float iv = fsig(gg.x), fv = fsig(gg.y), gv = ftanh(gg.z), ov = fsig(gg.w);
                float c2 = fv * creg[i][uu] + iv * gv;
                if (k != 0) creg[i][uu] = c2;    // filter update only for k>=1
                c2v[uu] = c2;
                h2v[uu] = ov * ftanh(c2);
            }
            cstore8(chainH + slotBase + fmoff(lrow, tn * 32 + ub),
                    pack4bf(f2bf(h2v[0]), f2bf(h2v[1]), f2bf(h2v[2]), f2bf(h2v[3])));
            size_t pOff = slotBase + ((size_t)tn * 128 + lrow) * 32 + ub;
            *(ushort4*)(chainCb + pOff) =
                make_ushort4(f2bf(c2v[0]), f2bf(c2v[1]), f2bf(c2v[2]), f2bf(c2v[3]));
            if (k == 95) {
                size_t sOff = (size_t)l * SLOTE + (size_t)lrow * HID + tn * 32 + ub;
                *(float4*)(h_std + sOff) = make_float4(h2v[0], h2v[1], h2v[2], h2v[3]);
                *(float4*)(c_std + sOff) = make_float4(c2v[0], c2v[1], c2v[2], c2v[3]);
            }
            __syncthreads();   // drains vmcnt(0): all stores at coherence point
        }
        if (tid == 0)
            __hip_atomic_store((__attribute__((address_space(1))) int*)(fw(l, k + 1) + tn * 32),
                               1, __ATOMIC_RELAXED, __HIP_MEMORY_SCOPE_AGENT);
    }
}

// =====================================================================
// Phase B: GEMM+LSTM / GEMM+linear. NEW: 3-buffer 2-deep counted-vmcnt
// prefetch pipeline over 32-K panels (T3+T4): panel q+2 issued while
// panel q computes; vmcnt(4) in steady state (never drains to 0);
// single s_barrier per panel. FM layout keeps staging a pure linear
// DMA and fragment reads conflict-free.
// =====================================================================
struct GArgs {
    const u16* A1; const u16* A2;
    const u16 *B1, *B2;
    const float* bias;
    const u16* c_in; u16* cout_b;
    u16* h_out;
    u16* lin_out;
    int KP1, KP2;          // panels (K/32) per seg; 0 = absent
    int as1, as2;          // A tile stride (elements)
    int mode;
};

// Phase-B LDS: 3 x (8KB A panel + 8KB B panel) = 48KB; sG aliases.
union SMemB {
    u16 st[3][2][4096];
    float g[32][132];
};

// panel q of a FM tile: 8 strided 1KB chunks; wave stages chunks
// cp = wave*2 + c2 (cp = h2*4+i), global chunk c = (cp>>2)*8+(cp&3)*2+p
__device__ inline size_t pgoff(int q, int cp, int lane) {
    return (size_t)(q >> 1) * CHUNK
         + (size_t)(((cp >> 2) * 8) + ((cp & 3) * 2) + (q & 1)) * 512 + lane * 8;
}

// persistent LSTM-step GEMM: 768 blocks (3/CU), tn=bx&31, 4 tm tiles each
__global__ __launch_bounds__(256, 3) void gemm_lstm(GArgs g)
{
    __shared__ SMemB sm;
    const int tid = threadIdx.x;
    const int wave = tid >> 6, lane = tid & 63;
    const int wm = wave >> 1, wn = wave & 1;
    const int quad = lane >> 4, lc = lane & 15;
    const int tn = blockIdx.x & 31;
    const int tm0 = (blockIdx.x >> 5) * 4;
    const int frA = wm * 2048 + (quad * 16 + lc) * 8;   // + i*512 (panel-packed)
    const int frB = wn * 2048 + (quad * 16 + lc) * 8;   // + j*512

    const u16* B1p = g.B1 + (size_t)tn * g.KP1 * 4096;
    const u16* B2p = g.B2 + (size_t)tn * g.KP2 * 4096;
    const int NP = g.KP1 + g.KP2;

    for (int t = 0; t < 4; ++t) {
        const int tm = tm0 + t;
        const u16* A1t = g.A1 + (size_t)tm * g.as1;
        const u16* A2t = g.A2 + (size_t)tm * g.as2;

        auto issue = [&](int q, int buf) {
            const u16 *Ab, *Bb; int qq;
            if (q < g.KP1) { Ab = A1t; Bb = B1p; qq = q; }
            else           { Ab = A2t; Bb = B2p; qq = q - g.KP1; }
#pragma unroll
            for (int c2 = 0; c2 < 2; ++c2) {
                int cp = wave * 2 + c2;
                size_t go = pgoff(qq, cp, lane);
                gl2lds16(Ab + go, &sm.st[buf][0][cp * 512]);
                gl2lds16(Bb + go, &sm.st[buf][1][cp * 512]);
            }
        };

        f32x4 acc[4][4];
#pragma unroll
        for (int j = 0; j < 4; ++j) {
            float bvx = g.bias[tn * 128 + wn * 64 + j * 16 + lc];
            f32x4 bvv = {bvx, bvx, bvx, bvx};
#pragma unroll
            for (int i = 0; i < 4; ++i) acc[i][j] = bvv;
        }

        issue(0, 0);
        issue(1, 1);
        for (int q = 0; q < NP; ++q) {
            // panel q landed (4 DMAs/wave/panel; q+1 may stay in flight)
            if (q + 1 < NP) asm volatile("s_waitcnt vmcnt(4)" ::: "memory");
            else            asm volatile("s_waitcnt vmcnt(0)" ::: "memory");
            __builtin_amdgcn_s_barrier();    // all waves: landed + done MFMA(q-1)
            __builtin_amdgcn_sched_barrier(0);
            if (q + 2 < NP) issue(q + 2, (q + 2) % 3);
            const u16* la = sm.st[q % 3][0];
            const u16* lb = sm.st[q % 3][1];
            bf16x8 aF[4], bF[4];
#pragma unroll
            for (int i = 0; i < 4; ++i)
                aF[i] = *(const bf16x8*)&la[frA + i * 512];
#pragma unroll
            for (int j = 0; j < 4; ++j)
                bF[j] = *(const bf16x8*)&lb[frB + j * 512];
#pragma unroll
            for (int i = 0; i < 4; ++i)
#pragma unroll
                for (int j = 0; j < 4; ++j)
                    acc[i][j] = __builtin_amdgcn_mfma_f32_16x16x32_bf16(aF[i], bF[j], acc[i][j], 0, 0, 0);
        }
        __syncthreads();   // all MFMA reads done; sG (aliases st) now writable

        const int rl = tid >> 3, ub = (tid & 7) * 4;
#pragma unroll 1
        for (int i = 0; i < 4; ++i) {
#pragma unroll
            for (int j = 0; j < 4; ++j)
#pragma unroll
                for (int r = 0; r < 4; ++r)
                    sm.g[wm * 16 + quad * 4 + r][wn * 64 + j * 16 + lc] = acc[i][j][r];
            __syncthreads();
            int lrow = (rl >> 4) * 64 + i * 16 + (rl & 15);
            size_t pOff = (size_t)tm * SLOTE + ((size_t)tn * 128 + lrow) * 32 + ub;
            ushort4 co = *(const ushort4*)(g.c_in + pOff);
            float cold[4] = {bf2f(co.x), bf2f(co.y), bf2f(co.z), bf2f(co.w)};
            float c2v[4], h2v[4];
#pragma unroll
            for (int uu = 0; uu < 4; ++uu) {
                float4 gg = *(const float4*)&sm.g[rl][(ub + uu) * 4];
                float iv = fsig(gg.x), fv = fsig(gg.y), gv = ftanh(gg.z), ov = fsig(gg.w);
                float c2 = fv * cold[uu] + iv * gv;
                c2v[uu] = c2;
                h2v[uu] = ov * ftanh(c2);
            }
            *(ushort4*)(g.cout_b + pOff) =
                make_ushort4(f2bf(c2v[0]), f2bf(c2v[1]), f2bf(c2v[2]), f2bf(c2v[3]));
            *(ushort4*)(g.h_out + (size_t)tm * SLOTE + fmoff(lrow, tn * 32 + ub)) =
                make_ushort4(f2bf(h2v[0]), f2bf(h2v[1]), f2bf(h2v[2]), f2bf(h2v[3]));
            __syncthreads();
        }
    }
}

// linear-head GEMM: grid = 96 blocks (one per sample tile), tn = 0
__global__ __launch_bounds__(256, 3) void gemm_lin(GArgs g)
{
    __shared__ u16 st[3][2][4096];
    const int tid = threadIdx.x;
    const int wave = tid >> 6, lane = tid & 63;
    const int wm = wave >> 1, wn = wave & 1;
    const int quad = lane >> 4, lc = lane & 15;
    const int tm = blockIdx.x;
    const int frA = wm * 2048 + (quad * 16 + lc) * 8;
    const int frB = wn * 2048 + (quad * 16 + lc) * 8;

    const u16* A1t = g.A1 + (size_t)tm * g.as1;
    const int NP = g.KP1;

    auto issue = [&](int q, int buf) {
#pragma unroll
        for (int c2 = 0; c2 < 2; ++c2) {
            int cp = wave * 2 + c2;
            size_t go = pgoff(q, cp, lane);
            gl2lds16(A1t + go, &st[buf][0][cp * 512]);
            gl2lds16(g.B1 + go, &st[buf][1][cp * 512]);
        }
    };

    f32x4 acc[4][4];
#pragma unroll
    for (int j = 0; j < 4; ++j) {
        float bvx = g.bias[wn * 64 + j * 16 + lc];
        f32x4 bvv = {bvx, bvx, bvx, bvx};
#pragma unroll
        for (int i = 0; i < 4; ++i) acc[i][j] = bvv;
    }

    issue(0, 0);
    issue(1, 1);
    for (int q = 0; q < NP; ++q) {
        if (q + 1 < NP) asm volatile("s_waitcnt vmcnt(4)" ::: "memory");
        else            asm volatile("s_waitcnt vmcnt(0)" ::: "memory");
        __builtin_amdgcn_s_barrier();
        __builtin_amdgcn_sched_barrier(0);
        if (q + 2 < NP) issue(q + 2, (q + 2) % 3);
        const u16* la = st[q % 3][0];
        const u16* lb = st[q % 3][1];
        bf16x8 aF[4], bF[4];
#pragma unroll
        for (int i = 0; i < 4; ++i)
            aF[i] = *(const bf16x8*)&la[frA + i * 512];
#pragma unroll
        for (int j = 0; j < 4; ++j)
            bF[j] = *(const bf16x8*)&lb[frB + j * 512];
#pragma unroll
        for (int i = 0; i < 4; ++i)
#pragma unroll
            for (int j = 0; j < 4; ++j)
                acc[i][j] = __builtin_amdgcn_mfma_f32_16x16x32_bf16(aF[i], bF[j], acc[i][j], 0, 0, 0);
    }

    // pred tile in FM layout
#pragma unroll
    for (int i = 0; i < 4; ++i)
#pragma unroll
        for (int j = 0; j < 4; ++j)
#pragma unroll
            for (int r = 0; r < 4; ++r) {
                int grow = wm * 64 + i * 16 + quad * 4 + r;
                int gcol = wn * 64 + j * 16 + lc;
                g.lin_out[(size_t)tm * PREDT + fmoff(grow, gcol)] = f2bf(acc[i][j][r]);
            }
}

// ---- setup / epilogue kernels ----
__global__ void convert_weight(const float* __restrict__ src, u16* __restrict__ dst,
                               int kshift, int permute, int total) {
    int idx = blockIdx.x * 256 + threadIdx.x;
    if (idx >= total) return;
    const int K = 1 << kshift;
    int kk = idx & (K - 1);
    int rr = (idx >> kshift) & 127;
    int s = idx >> (kshift + 7);
    int jp = s * 128 + rr;
    int srow = permute ? ((jp & 3) * HID + (jp >> 2)) : jp;
    dst[((size_t)s << (kshift + 7)) + fmoff(rr, kk)] =
        f2bf(src[((size_t)srow << kshift) + kk]);
}

__global__ void conv_input(const float* __restrict__ in, u16* __restrict__ inb) {
    int idx = blockIdx.x * 256 + threadIdx.x;  // 96*128*128
    int f = idx & 127;
    int b = (idx >> 7) & 127;
    int k = idx >> 14;
    inb[(size_t)k * PREDT + fmoff(b, f)] = f2bf(in[idx]);
}

__global__ void combine_bias(const float* __restrict__ bi, const float* __restrict__ bh,
                             float* __restrict__ dst) {
    int j = blockIdx.x * 256 + threadIdx.x;  // 4096
    int s = (j & 3) * HID + (j >> 2);
    dst[j] = bi[s] + bh[s];
}

__global__ void init_state(const float* __restrict__ h0, u16* __restrict__ chainH) {
    int idx = blockIdx.x * 256 + threadIdx.x;  // 2*BAT*HID
    int l = idx >> 17;
    int r = idx & (int)(SLOTE - 1);
    int b = r >> 10, hh = r & 1023;
    chainH[(size_t)l * 97 * SLOTE + fmoff(b, hh)] = f2bf(h0[idx]);
}

__global__ void init_flags(int* __restrict__ f) {
    int gid = blockIdx.x * 256 + threadIdx.x;
    if (gid >= FLAGN) return;
    int step = (gid >> 10) % 97;             // flag word stride 32 ints; 32 blocks/step
    f[gid] = ((gid & 31) == 0 && step == 0) ? 1 : 0;
}

__global__ void copy_next(const u16* __restrict__ predsb, float* __restrict__ out) {
    int idx = blockIdx.x * 256 + threadIdx.x;  // BAT*FEAT
    int b = idx >> 7, f = idx & 127;
    out[idx] = bf2f(predsb[(size_t)95 * PREDT + fmoff(b, f)]);
}

__global__ void gather_out(const float* __restrict__ inMusic, const u16* __restrict__ predsb,
                           float* __restrict__ outM) {
    int idx = blockIdx.x * 256 + threadIdx.x;  // 96*128*128*8
    int n = idx & 7;
    int f = (idx >> 3) & 127;
    int b = (idx >> 10) & 127;
    int r = idx >> 17;
    float v = 0.0f;
    if (r < NPRED && n >= r) {
        v = inMusic[((size_t)r * BAT + b) * FEAT + f];
    } else {
        int k = r - n - 1;
        if (n < k)
            v = bf2f(predsb[((size_t)n * NSAMP + k) * PREDT + fmoff(b, f)]);
    }
    outM[idx] = v;
}

__global__ void zero_out(float* __restrict__ o, int nmax) {
    int idx = blockIdx.x * 256 + threadIdx.x;
    if (idx < nmax) o[idx] = 0.0f;
}

extern "C" void kernel_launch(void* const* d_in, const int* in_sizes, int n_in,
                              void* d_out, int out_size, void* d_ws, size_t ws_size,
                              hipStream_t stream) {
    (void)in_sizes; (void)n_in;
    const float* inMusic = (const float*)d_in[0];
    const float* h0   = (const float*)d_in[1];
    const float* c0   = (const float*)d_in[2];
    const float* Wih0 = (const float*)d_in[3];
    const float* Whh0 = (const float*)d_in[4];
    const float* bih0 = (const float*)d_in[5];
    const float* bhh0 = (const float*)d_in[6];
    const float* Wih1 = (const float*)d_in[7];
    const float* Whh1 = (const float*)d_in[8];
    const float* bih1 = (const float*)d_in[9];
    const float* bhh1 = (const float*)d_in[10];
    const float* Wlin = (const float*)d_in[11];
    const float* blin = (const float*)d_in[12];
    float* out = (float*)d_out;

    const size_t OUT_H = (size_t)NSAMP * BAT * FEAT * NPRED;
    const size_t OUT_C = OUT_H + 2 * SLOTE;
    const size_t OUT_NEXT = OUT_C + 2 * SLOTE;

    char* ws = (char*)d_ws;
    size_t off = 0;
    auto alloc = [&](size_t bytes) {
        void* p = ws + off;
        off = (off + bytes + 255) & ~(size_t)255;
        return p;
    };
    u16* Wih0p = (u16*)alloc((size_t)GD * FEAT * 2);
    u16* Whh0p = (u16*)alloc((size_t)GD * HID * 2);
    u16* Wih1p = (u16*)alloc((size_t)GD * HID * 2);
    u16* Whh1p = (u16*)alloc((size_t)GD * HID * 2);
    u16* Wlinb = (u16*)alloc((size_t)FEAT * HID * 2);
    float* bp0 = (float*)alloc(GD * 4);
    float* bp1 = (float*)alloc(GD * 4);
    u16* chainH  = (u16*)alloc((size_t)2 * 97 * SLOTE * 2);
    u16* chainCb = (u16*)alloc((size_t)2 * 97 * SLOTE * 2);
    u16* hp2 = (u16*)alloc((size_t)2 * (size_t)NSAMP * SLOTE * 2);
    u16* predsb = (u16*)alloc((size_t)NPRED * NSAMP * PREDT * 2);
    u16* inb = (u16*)alloc((size_t)NSAMP * PREDT * 2);
    int* flags = (int*)alloc((size_t)FLAGN * 4);

    if (off > ws_size) {
        zero_out<<<(out_size + 255) / 256, 256, 0, stream>>>(out, out_size);
        return;
    }

    convert_weight<<<(GD * FEAT + 255) / 256, 256, 0, stream>>>(Wih0, Wih0p, 7, 1, GD * FEAT);
    convert_weight<<<(GD * HID + 255) / 256, 256, 0, stream>>>(Whh0, Whh0p, 10, 1, GD * HID);
    convert_weight<<<(GD * HID + 255) / 256, 256, 0, stream>>>(Wih1, Wih1p, 10, 1, GD * HID);
    convert_weight<<<(GD * HID + 255) / 256, 256, 0, stream>>>(Whh1, Whh1p, 10, 1, GD * HID);
    convert_weight<<<(FEAT * HID + 255) / 256, 256, 0, stream>>>(Wlin, Wlinb, 10, 0, FEAT * HID);
    conv_input<<<(NSAMP * BAT * FEAT) / 256, 256, 0, stream>>>(inMusic, inb);
    combine_bias<<<GD / 256, 256, 0, stream>>>(bih0, bhh0, bp0);
    combine_bias<<<GD / 256, 256, 0, stream>>>(bih1, bhh1, bp1);
    init_state<<<(int)(2 * SLOTE) / 256, 256, 0, stream>>>(h0, chainH);
    init_flags<<<(FLAGN + 255) / 256, 256, 0, stream>>>(flags);

    lstm_chain<<<64, 256, 0, stream>>>(
        inb, Wih0p, Whh0p, Wih1p, Whh1p, bp0, bp1, c0,
        chainH, chainCb, out + OUT_H, out + OUT_C, flags);

    auto Hs = [&](int l, int s) { return chainH + ((size_t)l * 97 + s) * SLOTE; };
    auto Cs = [&](int l, int s) { return chainCb + ((size_t)l * 97 + s) * SLOTE; };

    u16* hbuf0[2] = {Hs(0, 1), Hs(1, 1)};
    u16* hbuf1[2] = {hp2, hp2 + (size_t)NSAMP * SLOTE};
    u16* cB[2] = {Cs(0, 1), Cs(1, 1)};

    auto mkLin = [&](const u16* src, u16* dst) {
        GArgs a = {};
        a.A1 = src; a.KP1 = 32; a.as1 = (int)SLOTE; a.KP2 = 0;
        a.B1 = Wlinb; a.bias = blin;
        a.lin_out = dst; a.mode = 1;
        return a;
    };
    auto mkB = [&](int l, const u16* A1, int kp1, int as1, const u16* A2, u16* nxt) {
        GArgs a = {};
        a.A1 = A1; a.KP1 = kp1; a.as1 = as1;
        a.A2 = A2; a.KP2 = 32; a.as2 = (int)SLOTE;
        a.B1 = (l == 0) ? Wih0p : Wih1p; a.B2 = (l == 0) ? Whh0p : Whh1p;
        a.bias = (l == 0) ? bp0 : bp1;
        a.c_in = cB[l]; a.cout_b = cB[l];
        a.h_out = nxt; a.mode = 0;
        return a;
    };

    gemm_lin<<<96, 256, 0, stream>>>(mkLin(hbuf0[1], predsb));
    copy_next<<<(BAT * FEAT) / 256, 256, 0, stream>>>(predsb, out + OUT_NEXT);

    for (int n = 1; n < NPRED; ++n) {
        u16* cur0 = (n & 1) ? hbuf0[0] : hbuf1[0];
        u16* cur1 = (n & 1) ? hbuf0[1] : hbuf1[1];
        u16* nxt0 = (n & 1) ? hbuf1[0] : hbuf0[0];
        u16* nxt1 = (n & 1) ? hbuf1[1] : hbuf0[1];
        const u16* pin = predsb + (size_t)(n - 1) * NSAMP * PREDT;
        u16* pout = predsb + (size_t)n * NSAMP * PREDT;
        gemm_lstm<<<768, 256, 0, stream>>>(mkB(0, pin, 4, PREDT, cur0, nxt0));
        gemm_lstm<<<768, 256, 0, stream>>>(mkB(1, nxt0, 32, (int)SLOTE, cur1, nxt1));
        gemm_lin<<<96, 256, 0, stream>>>(mkLin(nxt1, pout));
    }

    gather_out<<<(NSAMP * BAT * FEAT * NPRED) / 256, 256, 0, stream>>>(inMusic, predsb, out);
}